// Round 1
// 1345.186 us; speedup vs baseline: 1.0274x; 1.0274x over previous
//
#include <hip/hip_runtime.h>

// PCmer forward: bf16-MFMA; phi_k fused INTO ctx (kp never hits HBM); phi_q+dinv+attn_out fused;
// GLU fused into pw1 (interleaved weights); fused QKV; ksum fused into ctx.
// R1: attn_fused LDS 76KB->30KB (alias phase1/phase2, chunked wave-local phi transpose,
//     ctx pre-transposed in ctx_reduce -> barrier-free PV loop, register-only dinv).
// L=6, B=4, N=2048, D=512, H=8, DH=64, ID=512, M=266, INNER=1024, K=31.

#define L_LAYERS 6
#define B_ 4
#define N_ 2048
#define D_ 512
#define H_ 8
#define DH_ 64
#define M_ 266
#define INNER_ 1024
#define T_ 8192            // B*N tokens
#define ROWS_ 65536        // B*N*H rows for phi
#define PS_ 320            // padded m stride (zeros in [266,320))
#define QKVS_ 1536         // qkv row stride
#define NS_ 4              // ctx n-splits

typedef __attribute__((ext_vector_type(8))) short short8;
typedef __attribute__((ext_vector_type(4))) float floatx4;

__device__ __forceinline__ ushort f2bf(float f) {
  union { float f; uint u; } v; v.f = f;
  uint r = v.u + 0x7fffu + ((v.u >> 16) & 1u);
  return (ushort)(r >> 16);
}
__device__ __forceinline__ float bf2f(ushort u) {
  union { uint u; float f; } v; v.u = ((uint)u) << 16;
  return v.f;
}
__device__ __forceinline__ float wave_sum(float v) {
#pragma unroll
  for (int m = 1; m < 64; m <<= 1) v += __shfl_xor(v, m);
  return v;
}
// async global->LDS, 16B per lane; dest = wave-uniform base + lane*16 (src per-lane)
__device__ __forceinline__ void async_cp16(const void* g, void* l) {
  __builtin_amdgcn_global_load_lds(
      (const __attribute__((address_space(1))) void*)g,
      (__attribute__((address_space(3))) void*)l, 16, 0, 0);
}

// ---------------- weight packing ----------------
__global__ void f2bf4_kernel(const float4* __restrict__ in, ushort* __restrict__ out, int n4) {
  int i = blockIdx.x * 256 + threadIdx.x;
  if (i < n4) {
    float4 v = in[i];
    ushort4 r;
    r.x = f2bf(v.x); r.y = f2bf(v.y); r.z = f2bf(v.z); r.w = f2bf(v.w);
    *(ushort4*)(out + (size_t)i * 4) = r;
  }
}
__global__ void pack_qkv_w(const float4* __restrict__ src, ushort* __restrict__ dst, int off) {
  int i = blockIdx.x * 256 + threadIdx.x;   // L*512*128
  if (i >= L_LAYERS * 512 * 128) return;
  int l = i >> 16;
  int rem = i & 65535;
  int row = rem >> 7, c4 = rem & 127;
  float4 v = src[i];
  ushort4 r;
  r.x = f2bf(v.x); r.y = f2bf(v.y); r.z = f2bf(v.z); r.w = f2bf(v.w);
  *(ushort4*)(dst + ((size_t)l * QKVS_ + off + row) * 512 + c4 * 4) = r;
}
__global__ void pack_qkv_b(const float* __restrict__ bq, const float* __restrict__ bk,
                           const float* __restrict__ bv, float* __restrict__ dst) {
  int i = blockIdx.x * 256 + threadIdx.x;   // L*1536
  if (i >= L_LAYERS * QKVS_) return;
  int l = i / QKVS_, c = i % QKVS_;
  dst[i] = c < 512 ? bq[l * 512 + c] : (c < 1024 ? bk[l * 512 + c - 512] : bv[l * 512 + c - 1024]);
}
__global__ void pad_proj(const float* __restrict__ proj, ushort* __restrict__ dst) {
  int i = blockIdx.x * 256 + threadIdx.x;   // L*320*64
  if (i >= L_LAYERS * 320 * 64) return;
  int l = i / (320 * 64), rem = i % (320 * 64), m = rem >> 6, kk = rem & 63;
  dst[i] = (m < M_) ? f2bf(proj[((size_t)l * M_ + m) * 64 + kk]) : (ushort)0;
}
// pw1 interleave: out col c' = 32b+16s+j16 -> src row s*1024 + 16b + j16
__global__ void pack_pw1_w(const float4* __restrict__ src, ushort* __restrict__ dst) {
  int i = blockIdx.x * 256 + threadIdx.x;   // L*2048*128
  if (i >= L_LAYERS * 2048 * 128) return;
  int l = i >> 18;
  int rem = i & 262143;
  int cp = rem >> 7, c4 = rem & 127;
  int s = (cp >> 4) & 1;
  int srow = ((cp >> 5) << 4) + (cp & 15) + s * 1024;
  float4 v = src[((size_t)l * 2048 + srow) * 128 + c4];
  ushort4 r;
  r.x = f2bf(v.x); r.y = f2bf(v.y); r.z = f2bf(v.z); r.w = f2bf(v.w);
  *(ushort4*)(dst + ((size_t)l * 2048 + cp) * 512 + c4 * 4) = r;
}
__global__ void pack_pw1_b(const float* __restrict__ src, float* __restrict__ dst) {
  int i = blockIdx.x * 256 + threadIdx.x;   // L*2048
  if (i >= L_LAYERS * 2048) return;
  int l = i >> 11, cp = i & 2047;
  int s = (cp >> 4) & 1;
  int srow = ((cp >> 5) << 4) + (cp & 15) + s * 1024;
  dst[i] = src[l * 2048 + srow];
}

// ---------------- layernorm (block per token, D=512), bf16 out ----------------
__global__ __launch_bounds__(256) void ln_kernel(const float* __restrict__ x,
                                                 const float* __restrict__ g,
                                                 const float* __restrict__ b,
                                                 ushort* __restrict__ out) {
  const int t = blockIdx.x;
  const int tid = threadIdx.x;
  const float* row = x + (size_t)t * D_;
  float v0 = row[tid], v1 = row[tid + 256];
  float s1 = v0 + v1;
  float s2 = v0 * v0 + v1 * v1;
  s1 = wave_sum(s1);
  s2 = wave_sum(s2);
  __shared__ float sh1[4], sh2[4];
  int w = tid >> 6;
  if ((tid & 63) == 0) { sh1[w] = s1; sh2[w] = s2; }
  __syncthreads();
  s1 = sh1[0] + sh1[1] + sh1[2] + sh1[3];
  s2 = sh2[0] + sh2[1] + sh2[2] + sh2[3];
  float mu = s1 * (1.f / D_);
  float var = s2 * (1.f / D_) - mu * mu;
  float rs = rsqrtf(var + 1e-5f);
  out[(size_t)t * D_ + tid]       = f2bf((v0 - mu) * rs * g[tid] + b[tid]);
  out[(size_t)t * D_ + tid + 256] = f2bf((v1 - mu) * rs * g[tid + 256] + b[tid + 256]);
}

// ---------------- bf16 MFMA GEMM (global_load_lds staging, XOR-swizzled LDS) -----------------
template <bool HAS_RES, bool OUT_BF16, int ACT>
__global__ __launch_bounds__(256) void gemm_mfma(const ushort* __restrict__ A,
                                                 const ushort* __restrict__ W,
                                                 const float* __restrict__ bias,
                                                 const float* __restrict__ res,
                                                 void* __restrict__ Cout,
                                                 int K, int ldc) {
  __shared__ ushort As[128 * 32];
  __shared__ ushort Bs[128 * 32];
  const int tid = threadIdx.x;
  const int w = tid >> 6, lane = tid & 63;
  const int row0 = blockIdx.x * 128, col0 = blockIdx.y * 128;
  const int rl = lane >> 2;
  const int lc = ((lane & 3) ^ ((lane >> 3) & 3)) * 8;
  const ushort* gA0 = A + (size_t)(row0 + w * 32 + rl) * K + lc;
  const ushort* gA1 = gA0 + (size_t)16 * K;
  const ushort* gB0 = W + (size_t)(col0 + w * 32 + rl) * K + lc;
  const ushort* gB1 = gB0 + (size_t)16 * K;
  ushort* lA = As + w * 1024;
  ushort* lB = Bs + w * 1024;
  const int m16 = lane & 15, quad = lane >> 4;
  const int awr = (w >> 1) * 64, bwc = (w & 1) * 64;
  floatx4 acc[4][4] = {};
  for (int k0 = 0; k0 < K; k0 += 32) {
    __syncthreads();
    async_cp16(gA0 + k0, lA);
    async_cp16(gA1 + k0, lA + 512);
    async_cp16(gB0 + k0, lB);
    async_cp16(gB1 + k0, lB + 512);
    __syncthreads();
    short8 af[4], bfr[4];
#pragma unroll
    for (int i = 0; i < 4; i++) {
      int r = awr + i * 16 + m16;
      af[i] = *(const short8*)&As[r * 32 + (quad ^ ((r >> 1) & 3)) * 8];
    }
#pragma unroll
    for (int j = 0; j < 4; j++) {
      int r = bwc + j * 16 + m16;
      bfr[j] = *(const short8*)&Bs[r * 32 + (quad ^ ((r >> 1) & 3)) * 8];
    }
#pragma unroll
    for (int i = 0; i < 4; i++)
#pragma unroll
      for (int j = 0; j < 4; j++)
        acc[i][j] = __builtin_amdgcn_mfma_f32_16x16x32_bf16(af[i], bfr[j], acc[i][j], 0, 0, 0);
  }
  if (ACT == 0) {
#pragma unroll
    for (int i = 0; i < 4; i++) {
      const int r0 = row0 + awr + i * 16 + quad * 4;
#pragma unroll
      for (int j = 0; j < 4; j++) {
        const int c = col0 + bwc + j * 16 + m16;
        const float bv = bias[c];
#pragma unroll
        for (int r = 0; r < 4; r++) {
          float vv = acc[i][j][r] + bv;
          if (HAS_RES) vv += res[(size_t)(r0 + r) * ldc + c];
          if (OUT_BF16) ((ushort*)Cout)[(size_t)(r0 + r) * ldc + c] = f2bf(vv);
          else          ((float*)Cout)[(size_t)(r0 + r) * ldc + c] = vv;
        }
      }
    }
  } else {
    // GLU epilogue on interleaved columns: z = (a+ba)*sigmoid(g+bg)
#pragma unroll
    for (int i = 0; i < 4; i++) {
      const int r0 = row0 + awr + i * 16 + quad * 4;
#pragma unroll
      for (int jp = 0; jp < 2; jp++) {
        const int j = jp * 2;
        const int ca = col0 + bwc + j * 16 + m16;
        const float ba = bias[ca], bg = bias[ca + 16];
        const int oc = ((col0 + bwc) >> 1) + jp * 16 + m16;
#pragma unroll
        for (int r = 0; r < 4; r++) {
          float a = acc[i][j][r] + ba;
          float g = acc[i][j + 1][r] + bg;
          float z = a / (1.f + expf(-g));
          ((ushort*)Cout)[(size_t)(r0 + r) * ldc + oc] = f2bf(z);
        }
      }
    }
  }
}

// ---------------- ctx with phi_k fused: kp computed in-LDS, never hits HBM ----------------
// grid (bh=32, mt=5, ns=NS_). For each 32-token chunk: stage raw k-tile, MFMA vs LDS proj
// slice, FAVOR key epilogue in-register -> swizzled kps LDS; then ctx MFMA + ksum partials.
__global__ __launch_bounds__(256) void ctx_phi_mfma(const ushort* __restrict__ qkv,
                                                    const ushort* __restrict__ projp,
                                                    float* __restrict__ part,
                                                    float* __restrict__ kpart) {
  __shared__ ushort projs[64 * 64];  // proj rows m0..m0+63, XOR-chunk layout
  __shared__ ushort kts[32 * 64];    // raw k tile, XOR-chunk layout
  __shared__ ushort kps[64][40];     // phi^T [m][n swizzled]
  __shared__ ushort vsT[64][40];     // v^T  [e][n swizzled]
  __shared__ float diag_sh[32];
  __shared__ float kshare[4][64];
  const int bh = blockIdx.x, mt = blockIdx.y, ns = blockIdx.z;
  const int b = bh >> 3, h = bh & 7;
  const int m0 = mt * 64;
  const int tid = threadIdx.x;
  const int w = tid >> 6, lane = tid & 63, l16 = lane & 15, quad = lane >> 4;
  const int rl8 = lane >> 3;
  const int lc8 = ((lane & 7) ^ (rl8 & 7)) * 8;
  // stage proj slice once (rows m0..m0+63)
#pragma unroll
  for (int j = 0; j < 2; j++) {
    const int rb = w * 16 + j * 8;
    async_cp16(projp + (size_t)(m0 + rb + rl8) * 64 + lc8, projs + rb * 64);
  }
  // v scatter mapping (n = nn, e-octet a8)
  const int nn = tid >> 3;
  const int a8 = tid & 7;
  const int gn = nn >> 3, jn = nn & 7;
  const int pc = ((gn ^ (a8 & 3)) << 3) | jn;
  const int km = tid & 63, kg = tid >> 6;  // ksum mapping
  const float dn = 0.35355339059327373f;   // 64^-0.25
  const float ratio = 0.06131393394849658f;
  floatx4 acc[4] = {};
  float ksp = 0.f;
  for (int nstep = 0; nstep < 2048 / NS_ / 32; nstep++) {
    const int n0 = ns * (2048 / NS_) + nstep * 32;
    // stage raw k tile (32 tokens x 64 dh): wave w stages rows w*8..w*8+7
    {
      const int rb = w * 8;
      async_cp16(qkv + (size_t)(b * N_ + n0 + rb + rl8) * QKVS_ + 512 + h * 64 + lc8,
                 kts + rb * 64);
    }
    uint4 vv = *(const uint4*)(qkv + ((size_t)(b * N_ + n0 + nn)) * QKVS_ + 1024 + h * 64 + a8 * 8);
    __syncthreads();   // [A] prev-iter LDS reads done; kts staged (barrier drains vmcnt)
    // diag per token: 8 lanes per row
    {
      const int r = tid >> 3;        // 0..31
      const int c = tid & 7;
      short8 kv8 = *(const short8*)&kts[r * 64 + c * 8];
      const ushort* u = (const ushort*)&kv8;
      float s = 0.f;
#pragma unroll
      for (int j = 0; j < 8; j++) { float f = bf2f(u[j]); s += f * f; }
      s += __shfl_xor(s, 1);
      s += __shfl_xor(s, 2);
      s += __shfl_xor(s, 4);
      if ((tid & 7) == 0) diag_sh[r] = 0.0625f * s;   // 0.5*dn^2
    }
    // v scatter into vsT
    {
      const ushort* ve = (const ushort*)&vv;
#pragma unroll
      for (int j = 0; j < 8; j++) vsT[a8 * 8 + j][pc] = ve[j];
    }
    __syncthreads();   // [B] diag + vsT + kts visible
    // phi MFMA: out[m=64][n=32]; wave w -> m rows w*16..w*16+15
    floatx4 pacc[2] = {};
#pragma unroll
    for (int s = 0; s < 2; s++) {
      const int ar = w * 16 + l16;
      short8 af = *(const short8*)&projs[ar * 64 + ((s * 4 + quad) ^ (ar & 7)) * 8];
#pragma unroll
      for (int nj = 0; nj < 2; nj++) {
        const int br = nj * 16 + l16;
        short8 bf = *(const short8*)&kts[br * 64 + ((s * 4 + quad) ^ (br & 7)) * 8];
        pacc[nj] = __builtin_amdgcn_mfma_f32_16x16x32_bf16(af, bf, pacc[nj], 0, 0, 0);
      }
    }
    // FAVOR key epilogue -> kps (swizzled scatter)
#pragma unroll
    for (int nj = 0; nj < 2; nj++) {
      const int n = nj * 16 + l16;
      const float dgn = diag_sh[n];
#pragma unroll
      for (int r = 0; r < 4; r++) {
        const int m = w * 16 + quad * 4 + r;
        float val = (m0 + m < M_) ? ratio * expf(dn * pacc[nj][r] - dgn + 1e-4f) : 0.f;
        kps[m][(((n >> 3) ^ ((m >> 3) & 3)) << 3) | (n & 7)] = f2bf(val);
      }
    }
    __syncthreads();   // [C] kps ready
    // ctx MFMA
    const int am = w * 16 + l16;
    const int apg = quad ^ ((am >> 3) & 3);
    short8 af = *(const short8*)&kps[am][apg * 8];
#pragma unroll
    for (int et = 0; et < 4; et++) {
      const int be = et * 16 + l16;
      const int bpg = quad ^ ((be >> 3) & 3);
      short8 bf = *(const short8*)&vsT[be][bpg * 8];
      acc[et] = __builtin_amdgcn_mfma_f32_16x16x32_bf16(af, bf, acc[et], 0, 0, 0);
    }
    // ksum partial (row km, physical chunk kg; permutation within row is sum-invariant)
    {
      short8 kr = *(const short8*)&kps[km][kg * 8];
      const ushort* ku = (const ushort*)&kr;
#pragma unroll
      for (int j = 0; j < 8; j++) ksp += bf2f(ku[j]);
    }
  }
  float* pb = part + ((size_t)(bh * NS_ + ns) * 5 + mt) * 4096;
#pragma unroll
  for (int et = 0; et < 4; et++)
#pragma unroll
    for (int r = 0; r < 4; r++)
      pb[(w * 16 + quad * 4 + r) * 64 + et * 16 + l16] = acc[et][r];
  kshare[kg][km] = ksp;
  __syncthreads();
  if (tid < 64)
    kpart[((size_t)(bh * NS_ + ns) * 5 + mt) * 64 + tid] =
        kshare[0][tid] + kshare[1][tid] + kshare[2][tid] + kshare[3][tid];
}

// ---------------- reduce partials -> ctxbT bf16 [bh][64 e][288 m] + ksum[bh][PS_] -------------
// Writes the context TRANSPOSED so attn_fused can load PV B-fragments directly from
// global (16B per lane, L2-resident) with no LDS scatter and no PV-loop barriers.
__global__ __launch_bounds__(256) void ctx_reduce(const float* __restrict__ part,
                                                  const float* __restrict__ kpart,
                                                  ushort* __restrict__ ctxbT,
                                                  float* __restrict__ ksum) {
  const int bh = blockIdx.x, mt = blockIdx.y;
  const int tid = threadIdx.x;
  const int w = tid >> 6, lane = tid & 63;
  // wave w handles m-octets oc = w, w+4 within this 64-m tile; lane = e (coalesced part reads)
  for (int oc = w; oc < 8; oc += 4) {
    const int mbase = mt * 64 + oc * 8;
    if (mbase < 288) {
      float s[8] = {0.f, 0.f, 0.f, 0.f, 0.f, 0.f, 0.f, 0.f};
#pragma unroll
      for (int ns = 0; ns < NS_; ns++) {
        const float* pb = part + ((size_t)(bh * NS_ + ns) * 5 + mt) * 4096;
#pragma unroll
        for (int ml = 0; ml < 8; ml++) s[ml] += pb[(oc * 8 + ml) * 64 + lane];
      }
      ushort tmp[8];
#pragma unroll
      for (int ml = 0; ml < 8; ml++) tmp[ml] = f2bf(s[ml]);
      *(short8*)(ctxbT + ((size_t)(bh * 64 + lane)) * 288 + mbase) = *(const short8*)tmp;
    }
  }
  if (tid < 64) {
    float s = 0.f;
#pragma unroll
    for (int ns = 0; ns < NS_; ns++)
      s += kpart[((size_t)(bh * NS_ + ns) * 5 + mt) * 64 + tid];
    ksum[(size_t)bh * PS_ + mt * 64 + tid] = s;
  }
}

// ---------------- fused phi_q + dinv + attn_out ----------------
// Phase 1: stage q tile + proj, 36 MFMAs into acc[18] (As/Bs in aliased LDS).
// Phase 2 (barrier-free): per 32-m chunk, FAVOR epilogue -> per-wave qst slab
// (wave-local 16x16 transpose), A-frag from qst, B-frag direct from global ctxbT.
// dinv kept entirely in registers. LDS: 28672 + 1152 + 256 = ~30KB -> 4+ blocks/CU.
__global__ __launch_bounds__(256, 4) void attn_fused(const ushort* __restrict__ qkv,
                                                     const ushort* __restrict__ projp,
                                                     const ushort* __restrict__ ctxbT,
                                                     const float* __restrict__ ksum,
                                                     ushort* __restrict__ o) {
  __shared__ __align__(16) ushort sm[14336];  // phase1: As[64*64]@0, Bs[160*64]@4096; phase2: qst
  __shared__ float ks_sh[288];
  __shared__ float diag_sh[64];
  ushort* As = sm;
  ushort* Bs = sm + 4096;
  ushort (*qst)[40] = (ushort(*)[40])sm;      // [64][40] per-wave 16-row slabs (aliases As)
  const int bh = blockIdx.x, b = bh >> 3, h = bh & 7;
  const int n0 = blockIdx.y * 64;
  const int tid = threadIdx.x;
  const int w = tid >> 6, lane = tid & 63, l16 = lane & 15, quad = lane >> 4;
  const int rl8 = lane >> 3;
  const int lc8 = ((lane & 7) ^ (rl8 & 7)) * 8;
#pragma unroll
  for (int j = 0; j < 2; j++) {
    const int rb = w * 16 + j * 8;
    async_cp16(qkv + (size_t)(b * N_ + n0 + rb + rl8) * QKVS_ + h * 64 + lc8, As + rb * 64);
  }
#pragma unroll
  for (int j = 0; j < 5; j++) {
    const int rb = w * 40 + j * 8;
    async_cp16(projp + (size_t)(rb + rl8) * 64 + lc8, Bs + rb * 64);
  }
  for (int i = tid; i < 288; i += 256) ks_sh[i] = ksum[(size_t)bh * PS_ + i];
  __syncthreads();
  {
    const int r = w * 16 + (lane >> 2);
    const int c0 = 2 * (lane & 3);
    float s = 0.f;
#pragma unroll
    for (int cc = 0; cc < 2; cc++) {
      short8 vv = *(const short8*)&As[r * 64 + ((c0 + cc) ^ (r & 7)) * 8];
      const ushort* u = (const ushort*)&vv;
#pragma unroll
      for (int j = 0; j < 8; j++) { float f = bf2f(u[j]); s += f * f; }
    }
    s += __shfl_xor(s, 1);
    s += __shfl_xor(s, 2);
    if ((lane & 3) == 0) diag_sh[r] = 0.0625f * s;
  }
  __syncthreads();
  float dgr[4];
#pragma unroll
  for (int r = 0; r < 4; r++) dgr[r] = diag_sh[w * 16 + quad * 4 + r];
  floatx4 acc[18];
#pragma unroll
  for (int cf = 0; cf < 18; cf++) acc[cf] = (floatx4){0.f, 0.f, 0.f, 0.f};
  const int ar = w * 16 + l16;
#pragma unroll
  for (int s = 0; s < 2; s++) {
    short8 af = *(const short8*)&As[ar * 64 + ((s * 4 + quad) ^ (ar & 7)) * 8];
#pragma unroll
    for (int cf = 0; cf < 10; cf++) {
      const int br = cf * 16 + l16;
      short8 bf = *(const short8*)&Bs[br * 64 + ((s * 4 + quad) ^ (br & 7)) * 8];
      acc[cf] = __builtin_amdgcn_mfma_f32_16x16x32_bf16(af, bf, acc[cf], 0, 0, 0);
    }
  }
  __syncthreads();
#pragma unroll
  for (int j = 0; j < 4; j++) {
    const int rb = w * 32 + j * 8;
    async_cp16(projp + (size_t)(160 + rb + rl8) * 64 + lc8, Bs + rb * 64);
  }
  __syncthreads();
#pragma unroll
  for (int s = 0; s < 2; s++) {
    short8 af = *(const short8*)&As[ar * 64 + ((s * 4 + quad) ^ (ar & 7)) * 8];
#pragma unroll
    for (int cf = 10; cf < 18; cf++) {
      const int br = (cf - 10) * 16 + l16;
      short8 bf = *(const short8*)&Bs[br * 64 + ((s * 4 + quad) ^ (br & 7)) * 8];
      acc[cf] = __builtin_amdgcn_mfma_f32_16x16x32_bf16(af, bf, acc[cf], 0, 0, 0);
    }
  }
  const float dn = 0.35355339059327373f;
  const float ratio = 0.06131393394849658f;
  float mxr[4];
#pragma unroll
  for (int r = 0; r < 4; r++) {
    float mx = -1e30f;
#pragma unroll
    for (int cf = 0; cf < 18; cf++) {
      const int col = cf * 16 + l16;
      if (col < M_) mx = fmaxf(mx, dn * acc[cf][r]);
    }
    mx = fmaxf(mx, __shfl_xor(mx, 1));
    mx = fmaxf(mx, __shfl_xor(mx, 2));
    mx = fmaxf(mx, __shfl_xor(mx, 4));
    mx = fmaxf(mx, __shfl_xor(mx, 8));
    mxr[r] = mx;
  }
  __syncthreads();  // phase-1 LDS reads complete before qst alias writes
  float dacc[4] = {0.f, 0.f, 0.f, 0.f};
  floatx4 acc2[4] = {};
  const ushort* ctxrow = ctxbT + (size_t)bh * (64 * 288);
  for (int m0 = 0; m0 < 288; m0 += 32) {
    const int cf0 = m0 >> 4;
    // FAVOR epilogue for this 32-m chunk -> per-wave qst slab (wave-local transpose)
#pragma unroll
    for (int cc = 0; cc < 2; cc++) {
      const int col = m0 + cc * 16 + l16;
      const float kv = ks_sh[col];
#pragma unroll
      for (int r = 0; r < 4; r++) {
        float val = (col < M_) ? ratio * (expf(dn * acc[cf0 + cc][r] - dgr[r] - mxr[r]) + 1e-4f)
                               : 0.f;
        qst[w * 16 + quad * 4 + r][cc * 16 + l16] = f2bf(val);
        dacc[r] += val * kv;
      }
    }
    // A-frag from own wave's slab (same-wave DS order is in-order; no barrier needed)
    short8 af = *(const short8*)&qst[w * 16 + l16][quad * 8];
#pragma unroll
    for (int et = 0; et < 4; et++) {
      short8 bf = *(const short8*)(ctxrow + (size_t)(et * 16 + l16) * 288 + m0 + quad * 8);
      acc2[et] = __builtin_amdgcn_mfma_f32_16x16x32_bf16(af, bf, acc2[et], 0, 0, 0);
    }
  }
  float di[4];
#pragma unroll
  for (int r = 0; r < 4; r++) {
    float d = dacc[r];
    d += __shfl_xor(d, 1);
    d += __shfl_xor(d, 2);
    d += __shfl_xor(d, 4);
    d += __shfl_xor(d, 8);
    di[r] = 1.f / (d + 1e-8f);
  }
#pragma unroll
  for (int r = 0; r < 4; r++) {
    const int n = n0 + w * 16 + quad * 4 + r;
#pragma unroll
    for (int et = 0; et < 4; et++)
      o[((size_t)(b * N_ + n)) * 512 + h * 64 + et * 16 + l16] = f2bf(acc2[et][r] * di[r]);
  }
}

// ---------------- depthwise conv K=31, pad 15, + bias + silu; bf16 in/out ----------------
#define TN_ 16
__global__ __launch_bounds__(256) void dwconv_kernel(const ushort* __restrict__ x,
                                                     const float* __restrict__ w,
                                                     const float* __restrict__ bias,
                                                     ushort* __restrict__ out) {
  const int bid = blockIdx.x;
  const int cb = bid & 3;
  const int nb = (bid >> 2) & 127;
  const int b  = bid >> 9;
  const int c = cb * 256 + threadIdx.x;
  const int n0 = nb * TN_;
  float win[TN_ + 30];
#pragma unroll
  for (int i = 0; i < TN_ + 30; i++) {
    int nn = n0 + i - 15;
    win[i] = (nn >= 0 && nn < N_) ? bf2f(x[(size_t)(b * N_ + nn) * INNER_ + c]) : 0.f;
  }
  float wc[31];
#pragma unroll
  for (int kk = 0; kk < 31; kk++) wc[kk] = w[c * 31 + kk];
  const float bsv = bias[c];
#pragma unroll
  for (int j = 0; j < TN_; j++) {
    float acc = bsv;
#pragma unroll
    for (int kk = 0; kk < 31; kk++) acc += win[j + kk] * wc[kk];
    acc = acc / (1.f + expf(-acc));
    out[(size_t)(b * N_ + n0 + j) * INNER_ + c] = f2bf(acc);
  }
}

// ---------------- host ----------------
extern "C" void kernel_launch(void* const* d_in, const int* in_sizes, int n_in,
                              void* d_out, int out_size, void* d_ws, size_t ws_size,
                              hipStream_t stream) {
  const float* in_x  = (const float*)d_in[0];
  const float* ln1_g = (const float*)d_in[1];
  const float* ln1_b = (const float*)d_in[2];
  const float* wq    = (const float*)d_in[3];
  const float* bq    = (const float*)d_in[4];
  const float* wk    = (const float*)d_in[5];
  const float* bk    = (const float*)d_in[6];
  const float* wv    = (const float*)d_in[7];
  const float* bv    = (const float*)d_in[8];
  const float* wo    = (const float*)d_in[9];
  const float* bo    = (const float*)d_in[10];
  const float* proj  = (const float*)d_in[11];
  const float* ln2_g = (const float*)d_in[12];
  const float* ln2_b = (const float*)d_in[13];
  const float* pw1_w = (const float*)d_in[14];
  const float* pw1_b = (const float*)d_in[15];
  const float* dw_w  = (const float*)d_in[16];
  const float* dw_b  = (const float*)d_in[17];
  const float* pw2_w = (const float*)d_in[18];
  const float* pw2_b = (const float*)d_in[19];

  char* cur = (char*)d_ws;
  auto alloc = [&](size_t bytes) { char* p = cur; cur += (bytes + 255) & ~(size_t)255; return p; };
  float*  x    = (float*)alloc((size_t)T_ * D_ * 4);
  ushort* p    = (ushort*)alloc((size_t)T_ * INNER_ * 2 * 2);      // glu+conv scratch
  float*  part = (float*)alloc((size_t)32 * NS_ * 5 * 4096 * 4);
  float*  kpart= (float*)alloc((size_t)32 * NS_ * 5 * 64 * 4);
  ushort* ctxb = (ushort*)alloc((size_t)32 * 288 * 64 * 2);        // holds ctx^T [bh][64][288]
  float*  ksum = (float*)alloc((size_t)32 * PS_ * 4);
  ushort* h    = (ushort*)alloc((size_t)T_ * D_ * 2);
  ushort* qkv  = (ushort*)alloc((size_t)T_ * QKVS_ * 2);
  ushort* obuf = (ushort*)alloc((size_t)T_ * D_ * 2);
  ushort* wqkv_b = (ushort*)alloc((size_t)L_LAYERS * QKVS_ * 512 * 2);
  float*  bqkv   = (float*)alloc((size_t)L_LAYERS * QKVS_ * 4);
  ushort* wo_b = (ushort*)alloc((size_t)L_LAYERS * D_ * D_ * 2);
  ushort* pjp  = (ushort*)alloc((size_t)L_LAYERS * 320 * 64 * 2);
  ushort* p1_b = (ushort*)alloc((size_t)L_LAYERS * 2048 * D_ * 2);
  float*  pb1  = (float*)alloc((size_t)L_LAYERS * 2048 * 4);
  ushort* p2_b = (ushort*)alloc((size_t)L_LAYERS * D_ * INNER_ * 2);
  ushort* glu  = p;
  ushort* conv = p + (size_t)T_ * INNER_;

  pack_qkv_w<<<(L_LAYERS * 512 * 128 + 255) / 256, 256, 0, stream>>>((const float4*)wq, wqkv_b, 0);
  pack_qkv_w<<<(L_LAYERS * 512 * 128 + 255) / 256, 256, 0, stream>>>((const float4*)wk, wqkv_b, 512);
  pack_qkv_w<<<(L_LAYERS * 512 * 128 + 255) / 256, 256, 0, stream>>>((const float4*)wv, wqkv_b, 1024);
  pack_qkv_b<<<(L_LAYERS * QKVS_ + 255) / 256, 256, 0, stream>>>(bq, bk, bv, bqkv);
  pad_proj<<<(L_LAYERS * 320 * 64 + 255) / 256, 256, 0, stream>>>(proj, pjp);
  pack_pw1_w<<<(L_LAYERS * 2048 * 128 + 255) / 256, 256, 0, stream>>>((const float4*)pw1_w, p1_b);
  pack_pw1_b<<<(L_LAYERS * 2048 + 255) / 256, 256, 0, stream>>>(pw1_b, pb1);
  {
    int n4 = L_LAYERS * D_ * D_ / 4;
    f2bf4_kernel<<<(n4 + 255) / 256, 256, 0, stream>>>((const float4*)wo, wo_b, n4);
    n4 = L_LAYERS * D_ * INNER_ / 4;
    f2bf4_kernel<<<(n4 + 255) / 256, 256, 0, stream>>>((const float4*)pw2_w, p2_b, n4);
  }

  for (int l = 0; l < L_LAYERS; l++) {
    const ushort* wqkvl = wqkv_b + (size_t)l * QKVS_ * 512;
    const ushort* wol = wo_b + (size_t)l * D_ * D_;
    const ushort* pjl = pjp + (size_t)l * 320 * 64;
    const ushort* p1l = p1_b + (size_t)l * 2048 * D_;
    const ushort* p2l = p2_b + (size_t)l * D_ * INNER_;
    const float*  dwl = dw_w + (size_t)l * INNER_ * 31;
    const float*  xin = (l == 0) ? in_x : x;
    float* xout = (l == L_LAYERS - 1) ? (float*)d_out : x;

    ln_kernel<<<T_, 256, 0, stream>>>(xin, ln1_g + l * D_, ln1_b + l * D_, h);
    gemm_mfma<false, true, 0><<<dim3(T_ / 128, QKVS_ / 128), 256, 0, stream>>>(
        h, wqkvl, bqkv + (size_t)l * QKVS_, nullptr, qkv, D_, QKVS_);
    ctx_phi_mfma<<<dim3(32, 5, NS_), 256, 0, stream>>>(qkv, pjl, part, kpart);
    ctx_reduce<<<dim3(32, 5), 256, 0, stream>>>(part, kpart, ctxb, ksum);
    attn_fused<<<dim3(32, 32), 256, 0, stream>>>(qkv, pjl, ctxb, ksum, obuf);
    gemm_mfma<true, false, 0><<<dim3(T_ / 128, 4), 256, 0, stream>>>(
        obuf, wol, bo + l * D_, xin, x, D_, D_);
    ln_kernel<<<T_, 256, 0, stream>>>(x, ln2_g + l * D_, ln2_b + l * D_, h);
    gemm_mfma<false, true, 1><<<dim3(T_ / 128, 16), 256, 0, stream>>>(
        h, p1l, pb1 + (size_t)l * 2048, nullptr, glu, D_, INNER_);
    dwconv_kernel<<<B_ * (N_ / TN_) * 4, 256, 0, stream>>>(glu, dwl, dw_b + l * INNER_, conv);
    gemm_mfma<true, false, 0><<<dim3(T_ / 128, 4), 256, 0, stream>>>(
        conv, p2l, pw2_b + l * D_, x, xout, INNER_, D_);
  }
}

// Round 2
// 1303.808 us; speedup vs baseline: 1.0600x; 1.0317x over previous
//
#include <hip/hip_runtime.h>

// PCmer forward: bf16-MFMA; phi_k fused INTO ctx (kp never hits HBM); phi_q+dinv+attn_out fused;
// GLU fused into pw1 (interleaved weights); fused QKV; ksum fused into ctx.
// R1: attn_fused LDS 76KB->30KB, ctx pre-transposed, barrier-free PV loop.
// R2: gemm_mfma double-buffered LDS + 1-deep prefetch (stage next tile BEFORE compute,
//     single barrier per K-step) -- hides global->LDS latency under MFMA.
// L=6, B=4, N=2048, D=512, H=8, DH=64, ID=512, M=266, INNER=1024, K=31.

#define L_LAYERS 6
#define B_ 4
#define N_ 2048
#define D_ 512
#define H_ 8
#define DH_ 64
#define M_ 266
#define INNER_ 1024
#define T_ 8192            // B*N tokens
#define ROWS_ 65536        // B*N*H rows for phi
#define PS_ 320            // padded m stride (zeros in [266,320))
#define QKVS_ 1536         // qkv row stride
#define NS_ 4              // ctx n-splits

typedef __attribute__((ext_vector_type(8))) short short8;
typedef __attribute__((ext_vector_type(4))) float floatx4;

__device__ __forceinline__ ushort f2bf(float f) {
  union { float f; uint u; } v; v.f = f;
  uint r = v.u + 0x7fffu + ((v.u >> 16) & 1u);
  return (ushort)(r >> 16);
}
__device__ __forceinline__ float bf2f(ushort u) {
  union { uint u; float f; } v; v.u = ((uint)u) << 16;
  return v.f;
}
__device__ __forceinline__ float wave_sum(float v) {
#pragma unroll
  for (int m = 1; m < 64; m <<= 1) v += __shfl_xor(v, m);
  return v;
}
// async global->LDS, 16B per lane; dest = wave-uniform base + lane*16 (src per-lane)
__device__ __forceinline__ void async_cp16(const void* g, void* l) {
  __builtin_amdgcn_global_load_lds(
      (const __attribute__((address_space(1))) void*)g,
      (__attribute__((address_space(3))) void*)l, 16, 0, 0);
}

// ---------------- weight packing ----------------
__global__ void f2bf4_kernel(const float4* __restrict__ in, ushort* __restrict__ out, int n4) {
  int i = blockIdx.x * 256 + threadIdx.x;
  if (i < n4) {
    float4 v = in[i];
    ushort4 r;
    r.x = f2bf(v.x); r.y = f2bf(v.y); r.z = f2bf(v.z); r.w = f2bf(v.w);
    *(ushort4*)(out + (size_t)i * 4) = r;
  }
}
__global__ void pack_qkv_w(const float4* __restrict__ src, ushort* __restrict__ dst, int off) {
  int i = blockIdx.x * 256 + threadIdx.x;   // L*512*128
  if (i >= L_LAYERS * 512 * 128) return;
  int l = i >> 16;
  int rem = i & 65535;
  int row = rem >> 7, c4 = rem & 127;
  float4 v = src[i];
  ushort4 r;
  r.x = f2bf(v.x); r.y = f2bf(v.y); r.z = f2bf(v.z); r.w = f2bf(v.w);
  *(ushort4*)(dst + ((size_t)l * QKVS_ + off + row) * 512 + c4 * 4) = r;
}
__global__ void pack_qkv_b(const float* __restrict__ bq, const float* __restrict__ bk,
                           const float* __restrict__ bv, float* __restrict__ dst) {
  int i = blockIdx.x * 256 + threadIdx.x;   // L*1536
  if (i >= L_LAYERS * QKVS_) return;
  int l = i / QKVS_, c = i % QKVS_;
  dst[i] = c < 512 ? bq[l * 512 + c] : (c < 1024 ? bk[l * 512 + c - 512] : bv[l * 512 + c - 1024]);
}
__global__ void pad_proj(const float* __restrict__ proj, ushort* __restrict__ dst) {
  int i = blockIdx.x * 256 + threadIdx.x;   // L*320*64
  if (i >= L_LAYERS * 320 * 64) return;
  int l = i / (320 * 64), rem = i % (320 * 64), m = rem >> 6, kk = rem & 63;
  dst[i] = (m < M_) ? f2bf(proj[((size_t)l * M_ + m) * 64 + kk]) : (ushort)0;
}
// pw1 interleave: out col c' = 32b+16s+j16 -> src row s*1024 + 16b + j16
__global__ void pack_pw1_w(const float4* __restrict__ src, ushort* __restrict__ dst) {
  int i = blockIdx.x * 256 + threadIdx.x;   // L*2048*128
  if (i >= L_LAYERS * 2048 * 128) return;
  int l = i >> 18;
  int rem = i & 262143;
  int cp = rem >> 7, c4 = rem & 127;
  int s = (cp >> 4) & 1;
  int srow = ((cp >> 5) << 4) + (cp & 15) + s * 1024;
  float4 v = src[((size_t)l * 2048 + srow) * 128 + c4];
  ushort4 r;
  r.x = f2bf(v.x); r.y = f2bf(v.y); r.z = f2bf(v.z); r.w = f2bf(v.w);
  *(ushort4*)(dst + ((size_t)l * 2048 + cp) * 512 + c4 * 4) = r;
}
__global__ void pack_pw1_b(const float* __restrict__ src, float* __restrict__ dst) {
  int i = blockIdx.x * 256 + threadIdx.x;   // L*2048
  if (i >= L_LAYERS * 2048) return;
  int l = i >> 11, cp = i & 2047;
  int s = (cp >> 4) & 1;
  int srow = ((cp >> 5) << 4) + (cp & 15) + s * 1024;
  dst[i] = src[l * 2048 + srow];
}

// ---------------- layernorm (block per token, D=512), bf16 out ----------------
__global__ __launch_bounds__(256) void ln_kernel(const float* __restrict__ x,
                                                 const float* __restrict__ g,
                                                 const float* __restrict__ b,
                                                 ushort* __restrict__ out) {
  const int t = blockIdx.x;
  const int tid = threadIdx.x;
  const float* row = x + (size_t)t * D_;
  float v0 = row[tid], v1 = row[tid + 256];
  float s1 = v0 + v1;
  float s2 = v0 * v0 + v1 * v1;
  s1 = wave_sum(s1);
  s2 = wave_sum(s2);
  __shared__ float sh1[4], sh2[4];
  int w = tid >> 6;
  if ((tid & 63) == 0) { sh1[w] = s1; sh2[w] = s2; }
  __syncthreads();
  s1 = sh1[0] + sh1[1] + sh1[2] + sh1[3];
  s2 = sh2[0] + sh2[1] + sh2[2] + sh2[3];
  float mu = s1 * (1.f / D_);
  float var = s2 * (1.f / D_) - mu * mu;
  float rs = rsqrtf(var + 1e-5f);
  out[(size_t)t * D_ + tid]       = f2bf((v0 - mu) * rs * g[tid] + b[tid]);
  out[(size_t)t * D_ + tid + 256] = f2bf((v1 - mu) * rs * g[tid + 256] + b[tid + 256]);
}

// ---------------- bf16 MFMA GEMM (double-buffered global_load_lds, 1-deep prefetch) ----------
// Per K-step: issue next tile's 4 global_load_lds into buf^1, ds_read+MFMA from buf, ONE
// __syncthreads (its vmcnt(0) drain pays only residual latency after compute overlap).
template <bool HAS_RES, bool OUT_BF16, int ACT>
__global__ __launch_bounds__(256) void gemm_mfma(const ushort* __restrict__ A,
                                                 const ushort* __restrict__ W,
                                                 const float* __restrict__ bias,
                                                 const float* __restrict__ res,
                                                 void* __restrict__ Cout,
                                                 int K, int ldc) {
  __shared__ ushort As[2][128 * 32];
  __shared__ ushort Bs[2][128 * 32];
  const int tid = threadIdx.x;
  const int w = tid >> 6, lane = tid & 63;
  const int row0 = blockIdx.x * 128, col0 = blockIdx.y * 128;
  const int rl = lane >> 2;
  const int lc = ((lane & 3) ^ ((lane >> 3) & 3)) * 8;
  const ushort* gA0 = A + (size_t)(row0 + w * 32 + rl) * K + lc;
  const ushort* gA1 = gA0 + (size_t)16 * K;
  const ushort* gB0 = W + (size_t)(col0 + w * 32 + rl) * K + lc;
  const ushort* gB1 = gB0 + (size_t)16 * K;
  const int m16 = lane & 15, quad = lane >> 4;
  const int awr = (w >> 1) * 64, bwc = (w & 1) * 64;
  floatx4 acc[4][4] = {};
  // prologue: stage k-tile 0 into buffer 0
  async_cp16(gA0, As[0] + w * 1024);
  async_cp16(gA1, As[0] + w * 1024 + 512);
  async_cp16(gB0, Bs[0] + w * 1024);
  async_cp16(gB1, Bs[0] + w * 1024 + 512);
  __syncthreads();
  int cur = 0;
  for (int k0 = 0; k0 < K; k0 += 32) {
    // prefetch next k-tile into the other buffer (issued BEFORE compute)
    if (k0 + 32 < K) {
      const int nxt = cur ^ 1;
      async_cp16(gA0 + k0 + 32, As[nxt] + w * 1024);
      async_cp16(gA1 + k0 + 32, As[nxt] + w * 1024 + 512);
      async_cp16(gB0 + k0 + 32, Bs[nxt] + w * 1024);
      async_cp16(gB1 + k0 + 32, Bs[nxt] + w * 1024 + 512);
    }
    short8 af[4], bfr[4];
#pragma unroll
    for (int i = 0; i < 4; i++) {
      int r = awr + i * 16 + m16;
      af[i] = *(const short8*)&As[cur][r * 32 + (quad ^ ((r >> 1) & 3)) * 8];
    }
#pragma unroll
    for (int j = 0; j < 4; j++) {
      int r = bwc + j * 16 + m16;
      bfr[j] = *(const short8*)&Bs[cur][r * 32 + (quad ^ ((r >> 1) & 3)) * 8];
    }
#pragma unroll
    for (int i = 0; i < 4; i++)
#pragma unroll
      for (int j = 0; j < 4; j++)
        acc[i][j] = __builtin_amdgcn_mfma_f32_16x16x32_bf16(af[i], bfr[j], acc[i][j], 0, 0, 0);
    __syncthreads();   // drains vmcnt -> buf^1 staged; protects buf reuse next iter
    cur ^= 1;
  }
  if (ACT == 0) {
#pragma unroll
    for (int i = 0; i < 4; i++) {
      const int r0 = row0 + awr + i * 16 + quad * 4;
#pragma unroll
      for (int j = 0; j < 4; j++) {
        const int c = col0 + bwc + j * 16 + m16;
        const float bv = bias[c];
#pragma unroll
        for (int r = 0; r < 4; r++) {
          float vv = acc[i][j][r] + bv;
          if (HAS_RES) vv += res[(size_t)(r0 + r) * ldc + c];
          if (OUT_BF16) ((ushort*)Cout)[(size_t)(r0 + r) * ldc + c] = f2bf(vv);
          else          ((float*)Cout)[(size_t)(r0 + r) * ldc + c] = vv;
        }
      }
    }
  } else {
    // GLU epilogue on interleaved columns: z = (a+ba)*sigmoid(g+bg)
#pragma unroll
    for (int i = 0; i < 4; i++) {
      const int r0 = row0 + awr + i * 16 + quad * 4;
#pragma unroll
      for (int jp = 0; jp < 2; jp++) {
        const int j = jp * 2;
        const int ca = col0 + bwc + j * 16 + m16;
        const float ba = bias[ca], bg = bias[ca + 16];
        const int oc = ((col0 + bwc) >> 1) + jp * 16 + m16;
#pragma unroll
        for (int r = 0; r < 4; r++) {
          float a = acc[i][j][r] + ba;
          float g = acc[i][j + 1][r] + bg;
          float z = a / (1.f + expf(-g));
          ((ushort*)Cout)[(size_t)(r0 + r) * ldc + oc] = f2bf(z);
        }
      }
    }
  }
}

// ---------------- ctx with phi_k fused: kp computed in-LDS, never hits HBM ----------------
// grid (bh=32, mt=5, ns=NS_). For each 32-token chunk: stage raw k-tile, MFMA vs LDS proj
// slice, FAVOR key epilogue in-register -> swizzled kps LDS; then ctx MFMA + ksum partials.
__global__ __launch_bounds__(256) void ctx_phi_mfma(const ushort* __restrict__ qkv,
                                                    const ushort* __restrict__ projp,
                                                    float* __restrict__ part,
                                                    float* __restrict__ kpart) {
  __shared__ ushort projs[64 * 64];  // proj rows m0..m0+63, XOR-chunk layout
  __shared__ ushort kts[32 * 64];    // raw k tile, XOR-chunk layout
  __shared__ ushort kps[64][40];     // phi^T [m][n swizzled]
  __shared__ ushort vsT[64][40];     // v^T  [e][n swizzled]
  __shared__ float diag_sh[32];
  __shared__ float kshare[4][64];
  const int bh = blockIdx.x, mt = blockIdx.y, ns = blockIdx.z;
  const int b = bh >> 3, h = bh & 7;
  const int m0 = mt * 64;
  const int tid = threadIdx.x;
  const int w = tid >> 6, lane = tid & 63, l16 = lane & 15, quad = lane >> 4;
  const int rl8 = lane >> 3;
  const int lc8 = ((lane & 7) ^ (rl8 & 7)) * 8;
  // stage proj slice once (rows m0..m0+63)
#pragma unroll
  for (int j = 0; j < 2; j++) {
    const int rb = w * 16 + j * 8;
    async_cp16(projp + (size_t)(m0 + rb + rl8) * 64 + lc8, projs + rb * 64);
  }
  // v scatter mapping (n = nn, e-octet a8)
  const int nn = tid >> 3;
  const int a8 = tid & 7;
  const int gn = nn >> 3, jn = nn & 7;
  const int pc = ((gn ^ (a8 & 3)) << 3) | jn;
  const int km = tid & 63, kg = tid >> 6;  // ksum mapping
  const float dn = 0.35355339059327373f;   // 64^-0.25
  const float ratio = 0.06131393394849658f;
  floatx4 acc[4] = {};
  float ksp = 0.f;
  for (int nstep = 0; nstep < 2048 / NS_ / 32; nstep++) {
    const int n0 = ns * (2048 / NS_) + nstep * 32;
    // stage raw k tile (32 tokens x 64 dh): wave w stages rows w*8..w*8+7
    {
      const int rb = w * 8;
      async_cp16(qkv + (size_t)(b * N_ + n0 + rb + rl8) * QKVS_ + 512 + h * 64 + lc8,
                 kts + rb * 64);
    }
    uint4 vv = *(const uint4*)(qkv + ((size_t)(b * N_ + n0 + nn)) * QKVS_ + 1024 + h * 64 + a8 * 8);
    __syncthreads();   // [A] prev-iter LDS reads done; kts staged (barrier drains vmcnt)
    // diag per token: 8 lanes per row
    {
      const int r = tid >> 3;        // 0..31
      const int c = tid & 7;
      short8 kv8 = *(const short8*)&kts[r * 64 + c * 8];
      const ushort* u = (const ushort*)&kv8;
      float s = 0.f;
#pragma unroll
      for (int j = 0; j < 8; j++) { float f = bf2f(u[j]); s += f * f; }
      s += __shfl_xor(s, 1);
      s += __shfl_xor(s, 2);
      s += __shfl_xor(s, 4);
      if ((tid & 7) == 0) diag_sh[r] = 0.0625f * s;   // 0.5*dn^2
    }
    // v scatter into vsT
    {
      const ushort* ve = (const ushort*)&vv;
#pragma unroll
      for (int j = 0; j < 8; j++) vsT[a8 * 8 + j][pc] = ve[j];
    }
    __syncthreads();   // [B] diag + vsT + kts visible
    // phi MFMA: out[m=64][n=32]; wave w -> m rows w*16..w*16+15
    floatx4 pacc[2] = {};
#pragma unroll
    for (int s = 0; s < 2; s++) {
      const int ar = w * 16 + l16;
      short8 af = *(const short8*)&projs[ar * 64 + ((s * 4 + quad) ^ (ar & 7)) * 8];
#pragma unroll
      for (int nj = 0; nj < 2; nj++) {
        const int br = nj * 16 + l16;
        short8 bf = *(const short8*)&kts[br * 64 + ((s * 4 + quad) ^ (br & 7)) * 8];
        pacc[nj] = __builtin_amdgcn_mfma_f32_16x16x32_bf16(af, bf, pacc[nj], 0, 0, 0);
      }
    }
    // FAVOR key epilogue -> kps (swizzled scatter)
#pragma unroll
    for (int nj = 0; nj < 2; nj++) {
      const int n = nj * 16 + l16;
      const float dgn = diag_sh[n];
#pragma unroll
      for (int r = 0; r < 4; r++) {
        const int m = w * 16 + quad * 4 + r;
        float val = (m0 + m < M_) ? ratio * expf(dn * pacc[nj][r] - dgn + 1e-4f) : 0.f;
        kps[m][(((n >> 3) ^ ((m >> 3) & 3)) << 3) | (n & 7)] = f2bf(val);
      }
    }
    __syncthreads();   // [C] kps ready
    // ctx MFMA
    const int am = w * 16 + l16;
    const int apg = quad ^ ((am >> 3) & 3);
    short8 af = *(const short8*)&kps[am][apg * 8];
#pragma unroll
    for (int et = 0; et < 4; et++) {
      const int be = et * 16 + l16;
      const int bpg = quad ^ ((be >> 3) & 3);
      short8 bf = *(const short8*)&vsT[be][bpg * 8];
      acc[et] = __builtin_amdgcn_mfma_f32_16x16x32_bf16(af, bf, acc[et], 0, 0, 0);
    }
    // ksum partial (row km, physical chunk kg; permutation within row is sum-invariant)
    {
      short8 kr = *(const short8*)&kps[km][kg * 8];
      const ushort* ku = (const ushort*)&kr;
#pragma unroll
      for (int j = 0; j < 8; j++) ksp += bf2f(ku[j]);
    }
  }
  float* pb = part + ((size_t)(bh * NS_ + ns) * 5 + mt) * 4096;
#pragma unroll
  for (int et = 0; et < 4; et++)
#pragma unroll
    for (int r = 0; r < 4; r++)
      pb[(w * 16 + quad * 4 + r) * 64 + et * 16 + l16] = acc[et][r];
  kshare[kg][km] = ksp;
  __syncthreads();
  if (tid < 64)
    kpart[((size_t)(bh * NS_ + ns) * 5 + mt) * 64 + tid] =
        kshare[0][tid] + kshare[1][tid] + kshare[2][tid] + kshare[3][tid];
}

// ---------------- reduce partials -> ctxbT bf16 [bh][64 e][288 m] + ksum[bh][PS_] -------------
// Writes the context TRANSPOSED so attn_fused can load PV B-fragments directly from
// global (16B per lane, L2-resident) with no LDS scatter and no PV-loop barriers.
__global__ __launch_bounds__(256) void ctx_reduce(const float* __restrict__ part,
                                                  const float* __restrict__ kpart,
                                                  ushort* __restrict__ ctxbT,
                                                  float* __restrict__ ksum) {
  const int bh = blockIdx.x, mt = blockIdx.y;
  const int tid = threadIdx.x;
  const int w = tid >> 6, lane = tid & 63;
  // wave w handles m-octets oc = w, w+4 within this 64-m tile; lane = e (coalesced part reads)
  for (int oc = w; oc < 8; oc += 4) {
    const int mbase = mt * 64 + oc * 8;
    if (mbase < 288) {
      float s[8] = {0.f, 0.f, 0.f, 0.f, 0.f, 0.f, 0.f, 0.f};
#pragma unroll
      for (int ns = 0; ns < NS_; ns++) {
        const float* pb = part + ((size_t)(bh * NS_ + ns) * 5 + mt) * 4096;
#pragma unroll
        for (int ml = 0; ml < 8; ml++) s[ml] += pb[(oc * 8 + ml) * 64 + lane];
      }
      ushort tmp[8];
#pragma unroll
      for (int ml = 0; ml < 8; ml++) tmp[ml] = f2bf(s[ml]);
      *(short8*)(ctxbT + ((size_t)(bh * 64 + lane)) * 288 + mbase) = *(const short8*)tmp;
    }
  }
  if (tid < 64) {
    float s = 0.f;
#pragma unroll
    for (int ns = 0; ns < NS_; ns++)
      s += kpart[((size_t)(bh * NS_ + ns) * 5 + mt) * 64 + tid];
    ksum[(size_t)bh * PS_ + mt * 64 + tid] = s;
  }
}

// ---------------- fused phi_q + dinv + attn_out ----------------
// Phase 1: stage q tile + proj, 36 MFMAs into acc[18] (As/Bs in aliased LDS).
// Phase 2 (barrier-free): per 32-m chunk, FAVOR epilogue -> per-wave qst slab
// (wave-local 16x16 transpose), A-frag from qst, B-frag direct from global ctxbT.
// dinv kept entirely in registers. LDS: 28672 + 1152 + 256 = ~30KB -> 4+ blocks/CU.
__global__ __launch_bounds__(256, 4) void attn_fused(const ushort* __restrict__ qkv,
                                                     const ushort* __restrict__ projp,
                                                     const ushort* __restrict__ ctxbT,
                                                     const float* __restrict__ ksum,
                                                     ushort* __restrict__ o) {
  __shared__ __align__(16) ushort sm[14336];  // phase1: As[64*64]@0, Bs[160*64]@4096; phase2: qst
  __shared__ float ks_sh[288];
  __shared__ float diag_sh[64];
  ushort* As = sm;
  ushort* Bs = sm + 4096;
  ushort (*qst)[40] = (ushort(*)[40])sm;      // [64][40] per-wave 16-row slabs (aliases As)
  const int bh = blockIdx.x, b = bh >> 3, h = bh & 7;
  const int n0 = blockIdx.y * 64;
  const int tid = threadIdx.x;
  const int w = tid >> 6, lane = tid & 63, l16 = lane & 15, quad = lane >> 4;
  const int rl8 = lane >> 3;
  const int lc8 = ((lane & 7) ^ (rl8 & 7)) * 8;
#pragma unroll
  for (int j = 0; j < 2; j++) {
    const int rb = w * 16 + j * 8;
    async_cp16(qkv + (size_t)(b * N_ + n0 + rb + rl8) * QKVS_ + h * 64 + lc8, As + rb * 64);
  }
#pragma unroll
  for (int j = 0; j < 5; j++) {
    const int rb = w * 40 + j * 8;
    async_cp16(projp + (size_t)(rb + rl8) * 64 + lc8, Bs + rb * 64);
  }
  for (int i = tid; i < 288; i += 256) ks_sh[i] = ksum[(size_t)bh * PS_ + i];
  __syncthreads();
  {
    const int r = w * 16 + (lane >> 2);
    const int c0 = 2 * (lane & 3);
    float s = 0.f;
#pragma unroll
    for (int cc = 0; cc < 2; cc++) {
      short8 vv = *(const short8*)&As[r * 64 + ((c0 + cc) ^ (r & 7)) * 8];
      const ushort* u = (const ushort*)&vv;
#pragma unroll
      for (int j = 0; j < 8; j++) { float f = bf2f(u[j]); s += f * f; }
    }
    s += __shfl_xor(s, 1);
    s += __shfl_xor(s, 2);
    if ((lane & 3) == 0) diag_sh[r] = 0.0625f * s;
  }
  __syncthreads();
  float dgr[4];
#pragma unroll
  for (int r = 0; r < 4; r++) dgr[r] = diag_sh[w * 16 + quad * 4 + r];
  floatx4 acc[18];
#pragma unroll
  for (int cf = 0; cf < 18; cf++) acc[cf] = (floatx4){0.f, 0.f, 0.f, 0.f};
  const int ar = w * 16 + l16;
#pragma unroll
  for (int s = 0; s < 2; s++) {
    short8 af = *(const short8*)&As[ar * 64 + ((s * 4 + quad) ^ (ar & 7)) * 8];
#pragma unroll
    for (int cf = 0; cf < 10; cf++) {
      const int br = cf * 16 + l16;
      short8 bf = *(const short8*)&Bs[br * 64 + ((s * 4 + quad) ^ (br & 7)) * 8];
      acc[cf] = __builtin_amdgcn_mfma_f32_16x16x32_bf16(af, bf, acc[cf], 0, 0, 0);
    }
  }
  __syncthreads();
#pragma unroll
  for (int j = 0; j < 4; j++) {
    const int rb = w * 32 + j * 8;
    async_cp16(projp + (size_t)(160 + rb + rl8) * 64 + lc8, Bs + rb * 64);
  }
  __syncthreads();
#pragma unroll
  for (int s = 0; s < 2; s++) {
    short8 af = *(const short8*)&As[ar * 64 + ((s * 4 + quad) ^ (ar & 7)) * 8];
#pragma unroll
    for (int cf = 10; cf < 18; cf++) {
      const int br = (cf - 10) * 16 + l16;
      short8 bf = *(const short8*)&Bs[br * 64 + ((s * 4 + quad) ^ (br & 7)) * 8];
      acc[cf] = __builtin_amdgcn_mfma_f32_16x16x32_bf16(af, bf, acc[cf], 0, 0, 0);
    }
  }
  const float dn = 0.35355339059327373f;
  const float ratio = 0.06131393394849658f;
  float mxr[4];
#pragma unroll
  for (int r = 0; r < 4; r++) {
    float mx = -1e30f;
#pragma unroll
    for (int cf = 0; cf < 18; cf++) {
      const int col = cf * 16 + l16;
      if (col < M_) mx = fmaxf(mx, dn * acc[cf][r]);
    }
    mx = fmaxf(mx, __shfl_xor(mx, 1));
    mx = fmaxf(mx, __shfl_xor(mx, 2));
    mx = fmaxf(mx, __shfl_xor(mx, 4));
    mx = fmaxf(mx, __shfl_xor(mx, 8));
    mxr[r] = mx;
  }
  __syncthreads();  // phase-1 LDS reads complete before qst alias writes
  float dacc[4] = {0.f, 0.f, 0.f, 0.f};
  floatx4 acc2[4] = {};
  const ushort* ctxrow = ctxbT + (size_t)bh * (64 * 288);
  for (int m0 = 0; m0 < 288; m0 += 32) {
    const int cf0 = m0 >> 4;
    // FAVOR epilogue for this 32-m chunk -> per-wave qst slab (wave-local transpose)
#pragma unroll
    for (int cc = 0; cc < 2; cc++) {
      const int col = m0 + cc * 16 + l16;
      const float kv = ks_sh[col];
#pragma unroll
      for (int r = 0; r < 4; r++) {
        float val = (col < M_) ? ratio * (expf(dn * acc[cf0 + cc][r] - dgr[r] - mxr[r]) + 1e-4f)
                               : 0.f;
        qst[w * 16 + quad * 4 + r][cc * 16 + l16] = f2bf(val);
        dacc[r] += val * kv;
      }
    }
    // A-frag from own wave's slab (same-wave DS order is in-order; no barrier needed)
    short8 af = *(const short8*)&qst[w * 16 + l16][quad * 8];
#pragma unroll
    for (int et = 0; et < 4; et++) {
      short8 bf = *(const short8*)(ctxrow + (size_t)(et * 16 + l16) * 288 + m0 + quad * 8);
      acc2[et] = __builtin_amdgcn_mfma_f32_16x16x32_bf16(af, bf, acc2[et], 0, 0, 0);
    }
  }
  float di[4];
#pragma unroll
  for (int r = 0; r < 4; r++) {
    float d = dacc[r];
    d += __shfl_xor(d, 1);
    d += __shfl_xor(d, 2);
    d += __shfl_xor(d, 4);
    d += __shfl_xor(d, 8);
    di[r] = 1.f / (d + 1e-8f);
  }
#pragma unroll
  for (int r = 0; r < 4; r++) {
    const int n = n0 + w * 16 + quad * 4 + r;
#pragma unroll
    for (int et = 0; et < 4; et++)
      o[((size_t)(b * N_ + n)) * 512 + h * 64 + et * 16 + l16] = f2bf(acc2[et][r] * di[r]);
  }
}

// ---------------- depthwise conv K=31, pad 15, + bias + silu; bf16 in/out ----------------
#define TN_ 16
__global__ __launch_bounds__(256) void dwconv_kernel(const ushort* __restrict__ x,
                                                     const float* __restrict__ w,
                                                     const float* __restrict__ bias,
                                                     ushort* __restrict__ out) {
  const int bid = blockIdx.x;
  const int cb = bid & 3;
  const int nb = (bid >> 2) & 127;
  const int b  = bid >> 9;
  const int c = cb * 256 + threadIdx.x;
  const int n0 = nb * TN_;
  float win[TN_ + 30];
#pragma unroll
  for (int i = 0; i < TN_ + 30; i++) {
    int nn = n0 + i - 15;
    win[i] = (nn >= 0 && nn < N_) ? bf2f(x[(size_t)(b * N_ + nn) * INNER_ + c]) : 0.f;
  }
  float wc[31];
#pragma unroll
  for (int kk = 0; kk < 31; kk++) wc[kk] = w[c * 31 + kk];
  const float bsv = bias[c];
#pragma unroll
  for (int j = 0; j < TN_; j++) {
    float acc = bsv;
#pragma unroll
    for (int kk = 0; kk < 31; kk++) acc += win[j + kk] * wc[kk];
    acc = acc / (1.f + expf(-acc));
    out[(size_t)(b * N_ + n0 + j) * INNER_ + c] = f2bf(acc);
  }
}

// ---------------- host ----------------
extern "C" void kernel_launch(void* const* d_in, const int* in_sizes, int n_in,
                              void* d_out, int out_size, void* d_ws, size_t ws_size,
                              hipStream_t stream) {
  const float* in_x  = (const float*)d_in[0];
  const float* ln1_g = (const float*)d_in[1];
  const float* ln1_b = (const float*)d_in[2];
  const float* wq    = (const float*)d_in[3];
  const float* bq    = (const float*)d_in[4];
  const float* wk    = (const float*)d_in[5];
  const float* bk    = (const float*)d_in[6];
  const float* wv    = (const float*)d_in[7];
  const float* bv    = (const float*)d_in[8];
  const float* wo    = (const float*)d_in[9];
  const float* bo    = (const float*)d_in[10];
  const float* proj  = (const float*)d_in[11];
  const float* ln2_g = (const float*)d_in[12];
  const float* ln2_b = (const float*)d_in[13];
  const float* pw1_w = (const float*)d_in[14];
  const float* pw1_b = (const float*)d_in[15];
  const float* dw_w  = (const float*)d_in[16];
  const float* dw_b  = (const float*)d_in[17];
  const float* pw2_w = (const float*)d_in[18];
  const float* pw2_b = (const float*)d_in[19];

  char* cur = (char*)d_ws;
  auto alloc = [&](size_t bytes) { char* p = cur; cur += (bytes + 255) & ~(size_t)255; return p; };
  float*  x    = (float*)alloc((size_t)T_ * D_ * 4);
  ushort* p    = (ushort*)alloc((size_t)T_ * INNER_ * 2 * 2);      // glu+conv scratch
  float*  part = (float*)alloc((size_t)32 * NS_ * 5 * 4096 * 4);
  float*  kpart= (float*)alloc((size_t)32 * NS_ * 5 * 64 * 4);
  ushort* ctxb = (ushort*)alloc((size_t)32 * 288 * 64 * 2);        // holds ctx^T [bh][64][288]
  float*  ksum = (float*)alloc((size_t)32 * PS_ * 4);
  ushort* h    = (ushort*)alloc((size_t)T_ * D_ * 2);
  ushort* qkv  = (ushort*)alloc((size_t)T_ * QKVS_ * 2);
  ushort* obuf = (ushort*)alloc((size_t)T_ * D_ * 2);
  ushort* wqkv_b = (ushort*)alloc((size_t)L_LAYERS * QKVS_ * 512 * 2);
  float*  bqkv   = (float*)alloc((size_t)L_LAYERS * QKVS_ * 4);
  ushort* wo_b = (ushort*)alloc((size_t)L_LAYERS * D_ * D_ * 2);
  ushort* pjp  = (ushort*)alloc((size_t)L_LAYERS * 320 * 64 * 2);
  ushort* p1_b = (ushort*)alloc((size_t)L_LAYERS * 2048 * D_ * 2);
  float*  pb1  = (float*)alloc((size_t)L_LAYERS * 2048 * 4);
  ushort* p2_b = (ushort*)alloc((size_t)L_LAYERS * D_ * INNER_ * 2);
  ushort* glu  = p;
  ushort* conv = p + (size_t)T_ * INNER_;

  pack_qkv_w<<<(L_LAYERS * 512 * 128 + 255) / 256, 256, 0, stream>>>((const float4*)wq, wqkv_b, 0);
  pack_qkv_w<<<(L_LAYERS * 512 * 128 + 255) / 256, 256, 0, stream>>>((const float4*)wk, wqkv_b, 512);
  pack_qkv_w<<<(L_LAYERS * 512 * 128 + 255) / 256, 256, 0, stream>>>((const float4*)wv, wqkv_b, 1024);
  pack_qkv_b<<<(L_LAYERS * QKVS_ + 255) / 256, 256, 0, stream>>>(bq, bk, bv, bqkv);
  pad_proj<<<(L_LAYERS * 320 * 64 + 255) / 256, 256, 0, stream>>>(proj, pjp);
  pack_pw1_w<<<(L_LAYERS * 2048 * 128 + 255) / 256, 256, 0, stream>>>((const float4*)pw1_w, p1_b);
  pack_pw1_b<<<(L_LAYERS * 2048 + 255) / 256, 256, 0, stream>>>(pw1_b, pb1);
  {
    int n4 = L_LAYERS * D_ * D_ / 4;
    f2bf4_kernel<<<(n4 + 255) / 256, 256, 0, stream>>>((const float4*)wo, wo_b, n4);
    n4 = L_LAYERS * D_ * INNER_ / 4;
    f2bf4_kernel<<<(n4 + 255) / 256, 256, 0, stream>>>((const float4*)pw2_w, p2_b, n4);
  }

  for (int l = 0; l < L_LAYERS; l++) {
    const ushort* wqkvl = wqkv_b + (size_t)l * QKVS_ * 512;
    const ushort* wol = wo_b + (size_t)l * D_ * D_;
    const ushort* pjl = pjp + (size_t)l * 320 * 64;
    const ushort* p1l = p1_b + (size_t)l * 2048 * D_;
    const ushort* p2l = p2_b + (size_t)l * D_ * INNER_;
    const float*  dwl = dw_w + (size_t)l * INNER_ * 31;
    const float*  dwbl = dw_b + (size_t)l * INNER_;
    const float*  xin = (l == 0) ? in_x : x;
    float* xout = (l == L_LAYERS - 1) ? (float*)d_out : x;

    ln_kernel<<<T_, 256, 0, stream>>>(xin, ln1_g + l * D_, ln1_b + l * D_, h);
    gemm_mfma<false, true, 0><<<dim3(T_ / 128, QKVS_ / 128), 256, 0, stream>>>(
        h, wqkvl, bqkv + (size_t)l * QKVS_, nullptr, qkv, D_, QKVS_);
    ctx_phi_mfma<<<dim3(32, 5, NS_), 256, 0, stream>>>(qkv, pjl, part, kpart);
    ctx_reduce<<<dim3(32, 5), 256, 0, stream>>>(part, kpart, ctxb, ksum);
    attn_fused<<<dim3(32, 32), 256, 0, stream>>>(qkv, pjl, ctxb, ksum, obuf);
    gemm_mfma<true, false, 0><<<dim3(T_ / 128, 4), 256, 0, stream>>>(
        obuf, wol, bo + l * D_, xin, x, D_, D_);
    ln_kernel<<<T_, 256, 0, stream>>>(x, ln2_g + l * D_, ln2_b + l * D_, h);
    gemm_mfma<false, true, 1><<<dim3(T_ / 128, 16), 256, 0, stream>>>(
        h, p1l, pb1 + (size_t)l * 2048, nullptr, glu, D_, INNER_);
    dwconv_kernel<<<B_ * (N_ / TN_) * 4, 256, 0, stream>>>(glu, dwl, dwbl, conv);
    gemm_mfma<true, false, 0><<<dim3(T_ / 128, 4), 256, 0, stream>>>(
        conv, p2l, pw2_b + l * D_, x, xout, INNER_, D_);
  }
}

// Round 3
// 1227.182 us; speedup vs baseline: 1.1262x; 1.0624x over previous
//
#include <hip/hip_runtime.h>

// PCmer forward: bf16-MFMA; phi_k fused INTO ctx (kp never hits HBM); phi_q+dinv+attn_out fused;
// GLU fused into pw1 (interleaved weights); fused QKV; ksum fused into ctx.
// R1: attn_fused LDS 76KB->30KB, ctx pre-transposed, barrier-free PV loop.
// R2: gemm_mfma double-buffered LDS + 1-deep prefetch.
// R3: gemm_mfma depth-2 pipeline, 3 LDS buffers, counted vmcnt(8) never drained to 0 in the
//     main loop (loads stay in flight ACROSS barriers, T3+T4); K templated for static tail.
//     ctx n-splits 4->8 (shorter serial chain, 5 blocks/CU).
// L=6, B=4, N=2048, D=512, H=8, DH=64, ID=512, M=266, INNER=1024, K=31.

#define L_LAYERS 6
#define B_ 4
#define N_ 2048
#define D_ 512
#define H_ 8
#define DH_ 64
#define M_ 266
#define INNER_ 1024
#define T_ 8192            // B*N tokens
#define PS_ 320            // padded m stride (zeros in [266,320))
#define QKVS_ 1536         // qkv row stride
#define NS_ 8              // ctx n-splits

typedef __attribute__((ext_vector_type(8))) short short8;
typedef __attribute__((ext_vector_type(4))) float floatx4;

__device__ __forceinline__ ushort f2bf(float f) {
  union { float f; uint u; } v; v.f = f;
  uint r = v.u + 0x7fffu + ((v.u >> 16) & 1u);
  return (ushort)(r >> 16);
}
__device__ __forceinline__ float bf2f(ushort u) {
  union { uint u; float f; } v; v.u = ((uint)u) << 16;
  return v.f;
}
__device__ __forceinline__ float wave_sum(float v) {
#pragma unroll
  for (int m = 1; m < 64; m <<= 1) v += __shfl_xor(v, m);
  return v;
}
// async global->LDS, 16B per lane; dest = wave-uniform base + lane*16 (src per-lane)
__device__ __forceinline__ void async_cp16(const void* g, void* l) {
  __builtin_amdgcn_global_load_lds(
      (const __attribute__((address_space(1))) void*)g,
      (__attribute__((address_space(3))) void*)l, 16, 0, 0);
}

// ---------------- weight packing ----------------
__global__ void f2bf4_kernel(const float4* __restrict__ in, ushort* __restrict__ out, int n4) {
  int i = blockIdx.x * 256 + threadIdx.x;
  if (i < n4) {
    float4 v = in[i];
    ushort4 r;
    r.x = f2bf(v.x); r.y = f2bf(v.y); r.z = f2bf(v.z); r.w = f2bf(v.w);
    *(ushort4*)(out + (size_t)i * 4) = r;
  }
}
__global__ void pack_qkv_w(const float4* __restrict__ src, ushort* __restrict__ dst, int off) {
  int i = blockIdx.x * 256 + threadIdx.x;   // L*512*128
  if (i >= L_LAYERS * 512 * 128) return;
  int l = i >> 16;
  int rem = i & 65535;
  int row = rem >> 7, c4 = rem & 127;
  float4 v = src[i];
  ushort4 r;
  r.x = f2bf(v.x); r.y = f2bf(v.y); r.z = f2bf(v.z); r.w = f2bf(v.w);
  *(ushort4*)(dst + ((size_t)l * QKVS_ + off + row) * 512 + c4 * 4) = r;
}
__global__ void pack_qkv_b(const float* __restrict__ bq, const float* __restrict__ bk,
                           const float* __restrict__ bv, float* __restrict__ dst) {
  int i = blockIdx.x * 256 + threadIdx.x;   // L*1536
  if (i >= L_LAYERS * QKVS_) return;
  int l = i / QKVS_, c = i % QKVS_;
  dst[i] = c < 512 ? bq[l * 512 + c] : (c < 1024 ? bk[l * 512 + c - 512] : bv[l * 512 + c - 1024]);
}
__global__ void pad_proj(const float* __restrict__ proj, ushort* __restrict__ dst) {
  int i = blockIdx.x * 256 + threadIdx.x;   // L*320*64
  if (i >= L_LAYERS * 320 * 64) return;
  int l = i / (320 * 64), rem = i % (320 * 64), m = rem >> 6, kk = rem & 63;
  dst[i] = (m < M_) ? f2bf(proj[((size_t)l * M_ + m) * 64 + kk]) : (ushort)0;
}
// pw1 interleave: out col c' = 32b+16s+j16 -> src row s*1024 + 16b + j16
__global__ void pack_pw1_w(const float4* __restrict__ src, ushort* __restrict__ dst) {
  int i = blockIdx.x * 256 + threadIdx.x;   // L*2048*128
  if (i >= L_LAYERS * 2048 * 128) return;
  int l = i >> 18;
  int rem = i & 262143;
  int cp = rem >> 7, c4 = rem & 127;
  int s = (cp >> 4) & 1;
  int srow = ((cp >> 5) << 4) + (cp & 15) + s * 1024;
  float4 v = src[((size_t)l * 2048 + srow) * 128 + c4];
  ushort4 r;
  r.x = f2bf(v.x); r.y = f2bf(v.y); r.z = f2bf(v.z); r.w = f2bf(v.w);
  *(ushort4*)(dst + ((size_t)l * 2048 + cp) * 512 + c4 * 4) = r;
}
__global__ void pack_pw1_b(const float* __restrict__ src, float* __restrict__ dst) {
  int i = blockIdx.x * 256 + threadIdx.x;   // L*2048
  if (i >= L_LAYERS * 2048) return;
  int l = i >> 11, cp = i & 2047;
  int s = (cp >> 4) & 1;
  int srow = ((cp >> 5) << 4) + (cp & 15) + s * 1024;
  dst[i] = src[l * 2048 + srow];
}

// ---------------- layernorm (block per token, D=512), bf16 out ----------------
__global__ __launch_bounds__(256) void ln_kernel(const float* __restrict__ x,
                                                 const float* __restrict__ g,
                                                 const float* __restrict__ b,
                                                 ushort* __restrict__ out) {
  const int t = blockIdx.x;
  const int tid = threadIdx.x;
  const float* row = x + (size_t)t * D_;
  float v0 = row[tid], v1 = row[tid + 256];
  float s1 = v0 + v1;
  float s2 = v0 * v0 + v1 * v1;
  s1 = wave_sum(s1);
  s2 = wave_sum(s2);
  __shared__ float sh1[4], sh2[4];
  int w = tid >> 6;
  if ((tid & 63) == 0) { sh1[w] = s1; sh2[w] = s2; }
  __syncthreads();
  s1 = sh1[0] + sh1[1] + sh1[2] + sh1[3];
  s2 = sh2[0] + sh2[1] + sh2[2] + sh2[3];
  float mu = s1 * (1.f / D_);
  float var = s2 * (1.f / D_) - mu * mu;
  float rs = rsqrtf(var + 1e-5f);
  out[(size_t)t * D_ + tid]       = f2bf((v0 - mu) * rs * g[tid] + b[tid]);
  out[(size_t)t * D_ + tid + 256] = f2bf((v1 - mu) * rs * g[tid + 256] + b[tid + 256]);
}

// ---------------- bf16 MFMA GEMM: depth-2 pipeline, 3 buffers, counted vmcnt ----------------
// Per main-loop step t: issue stage(t+2); vmcnt(8) retires only step-t's 4 loads (8 stay in
// flight across the barrier); s_barrier; ds_read buf[t%3]; lgkmcnt(0)+sched_barrier+s_barrier
// (WAR: next step stages into this buffer); 16 MFMAs. vmcnt never drains to 0 in the loop.
template <bool HAS_RES, bool OUT_BF16, int ACT, int KT>
__global__ __launch_bounds__(256) void gemm_mfma(const ushort* __restrict__ A,
                                                 const ushort* __restrict__ W,
                                                 const float* __restrict__ bias,
                                                 const float* __restrict__ res,
                                                 void* __restrict__ Cout,
                                                 int ldc) {
  constexpr int NT = KT / 32;
  __shared__ ushort As[3][128 * 32];
  __shared__ ushort Bs[3][128 * 32];
  const int tid = threadIdx.x;
  const int w = tid >> 6, lane = tid & 63;
  const int row0 = blockIdx.x * 128, col0 = blockIdx.y * 128;
  const int rl = lane >> 2;
  const int lc = ((lane & 3) ^ ((lane >> 3) & 3)) * 8;
  const ushort* gA0 = A + (size_t)(row0 + w * 32 + rl) * KT + lc;
  const ushort* gA1 = gA0 + (size_t)16 * KT;
  const ushort* gB0 = W + (size_t)(col0 + w * 32 + rl) * KT + lc;
  const ushort* gB1 = gB0 + (size_t)16 * KT;
  const int m16 = lane & 15, quad = lane >> 4;
  const int awr = (w >> 1) * 64, bwc = (w & 1) * 64;
  floatx4 acc[4][4] = {};

  auto stage = [&](int t, int buf) {
    async_cp16(gA0 + t * 32, As[buf] + w * 1024);
    async_cp16(gA1 + t * 32, As[buf] + w * 1024 + 512);
    async_cp16(gB0 + t * 32, Bs[buf] + w * 1024);
    async_cp16(gB1 + t * 32, Bs[buf] + w * 1024 + 512);
  };
  auto body = [&](int buf, bool bar2) {
    short8 af[4], bfr[4];
#pragma unroll
    for (int i = 0; i < 4; i++) {
      int r = awr + i * 16 + m16;
      af[i] = *(const short8*)&As[buf][r * 32 + (quad ^ ((r >> 1) & 3)) * 8];
    }
#pragma unroll
    for (int j = 0; j < 4; j++) {
      int r = bwc + j * 16 + m16;
      bfr[j] = *(const short8*)&Bs[buf][r * 32 + (quad ^ ((r >> 1) & 3)) * 8];
    }
    if (bar2) {
      asm volatile("s_waitcnt lgkmcnt(0)" ::: "memory");
      __builtin_amdgcn_sched_barrier(0);
      __builtin_amdgcn_s_barrier();
    }
#pragma unroll
    for (int i = 0; i < 4; i++)
#pragma unroll
      for (int j = 0; j < 4; j++)
        acc[i][j] = __builtin_amdgcn_mfma_f32_16x16x32_bf16(af[i], bfr[j], acc[i][j], 0, 0, 0);
  };

  // prologue: stage t=0 -> buf0, t=1 -> buf1 (8 loads in flight)
  stage(0, 0);
  stage(1, 1);
  int c = 0;
  for (int t = 0; t < NT - 2; t++) {
    int pf = c + 2; if (pf >= 3) pf -= 3;
    stage(t + 2, pf);                                   // +4 loads (12 in flight)
    asm volatile("s_waitcnt vmcnt(8)" ::: "memory");    // step-t's 4 landed; 8 stay in flight
    __builtin_amdgcn_s_barrier();                       // publish buf c to all waves
    body(c, true);                                      // reads, bar2 (WAR), MFMAs
    c++; if (c >= 3) c -= 3;
  }
  // t = NT-2: 8 loads in flight, retire this step's 4
  asm volatile("s_waitcnt vmcnt(4)" ::: "memory");
  __builtin_amdgcn_s_barrier();
  body(c, false);                                       // no more staging -> no WAR barrier
  c++; if (c >= 3) c -= 3;
  // t = NT-1
  asm volatile("s_waitcnt vmcnt(0)" ::: "memory");
  __builtin_amdgcn_s_barrier();
  body(c, false);

  if (ACT == 0) {
#pragma unroll
    for (int i = 0; i < 4; i++) {
      const int r0 = row0 + awr + i * 16 + quad * 4;
#pragma unroll
      for (int j = 0; j < 4; j++) {
        const int cc = col0 + bwc + j * 16 + m16;
        const float bv = bias[cc];
#pragma unroll
        for (int r = 0; r < 4; r++) {
          float vv = acc[i][j][r] + bv;
          if (HAS_RES) vv += res[(size_t)(r0 + r) * ldc + cc];
          if (OUT_BF16) ((ushort*)Cout)[(size_t)(r0 + r) * ldc + cc] = f2bf(vv);
          else          ((float*)Cout)[(size_t)(r0 + r) * ldc + cc] = vv;
        }
      }
    }
  } else {
    // GLU epilogue on interleaved columns: z = (a+ba)*sigmoid(g+bg)
#pragma unroll
    for (int i = 0; i < 4; i++) {
      const int r0 = row0 + awr + i * 16 + quad * 4;
#pragma unroll
      for (int jp = 0; jp < 2; jp++) {
        const int j = jp * 2;
        const int ca = col0 + bwc + j * 16 + m16;
        const float ba = bias[ca], bg = bias[ca + 16];
        const int oc = ((col0 + bwc) >> 1) + jp * 16 + m16;
#pragma unroll
        for (int r = 0; r < 4; r++) {
          float a = acc[i][j][r] + ba;
          float g = acc[i][j + 1][r] + bg;
          float z = a / (1.f + expf(-g));
          ((ushort*)Cout)[(size_t)(r0 + r) * ldc + oc] = f2bf(z);
        }
      }
    }
  }
}

// ---------------- ctx with phi_k fused: kp computed in-LDS, never hits HBM ----------------
// grid (bh=32, mt=5, ns=NS_). For each 32-token chunk: stage raw k-tile, MFMA vs LDS proj
// slice, FAVOR key epilogue in-register -> swizzled kps LDS; then ctx MFMA + ksum partials.
__global__ __launch_bounds__(256) void ctx_phi_mfma(const ushort* __restrict__ qkv,
                                                    const ushort* __restrict__ projp,
                                                    float* __restrict__ part,
                                                    float* __restrict__ kpart) {
  __shared__ ushort projs[64 * 64];  // proj rows m0..m0+63, XOR-chunk layout
  __shared__ ushort kts[32 * 64];    // raw k tile, XOR-chunk layout
  __shared__ ushort kps[64][40];     // phi^T [m][n swizzled]
  __shared__ ushort vsT[64][40];     // v^T  [e][n swizzled]
  __shared__ float diag_sh[32];
  __shared__ float kshare[4][64];
  const int bh = blockIdx.x, mt = blockIdx.y, ns = blockIdx.z;
  const int b = bh >> 3, h = bh & 7;
  const int m0 = mt * 64;
  const int tid = threadIdx.x;
  const int w = tid >> 6, lane = tid & 63, l16 = lane & 15, quad = lane >> 4;
  const int rl8 = lane >> 3;
  const int lc8 = ((lane & 7) ^ (rl8 & 7)) * 8;
  // stage proj slice once (rows m0..m0+63)
#pragma unroll
  for (int j = 0; j < 2; j++) {
    const int rb = w * 16 + j * 8;
    async_cp16(projp + (size_t)(m0 + rb + rl8) * 64 + lc8, projs + rb * 64);
  }
  // v scatter mapping (n = nn, e-octet a8)
  const int nn = tid >> 3;
  const int a8 = tid & 7;
  const int gn = nn >> 3, jn = nn & 7;
  const int pc = ((gn ^ (a8 & 3)) << 3) | jn;
  const int km = tid & 63, kg = tid >> 6;  // ksum mapping
  const float dn = 0.35355339059327373f;   // 64^-0.25
  const float ratio = 0.06131393394849658f;
  floatx4 acc[4] = {};
  float ksp = 0.f;
  for (int nstep = 0; nstep < 2048 / NS_ / 32; nstep++) {
    const int n0 = ns * (2048 / NS_) + nstep * 32;
    // stage raw k tile (32 tokens x 64 dh): wave w stages rows w*8..w*8+7
    {
      const int rb = w * 8;
      async_cp16(qkv + (size_t)(b * N_ + n0 + rb + rl8) * QKVS_ + 512 + h * 64 + lc8,
                 kts + rb * 64);
    }
    uint4 vv = *(const uint4*)(qkv + ((size_t)(b * N_ + n0 + nn)) * QKVS_ + 1024 + h * 64 + a8 * 8);
    __syncthreads();   // [A] prev-iter LDS reads done; kts staged (barrier drains vmcnt)
    // diag per token: 8 lanes per row
    {
      const int r = tid >> 3;        // 0..31
      const int c = tid & 7;
      short8 kv8 = *(const short8*)&kts[r * 64 + c * 8];
      const ushort* u = (const ushort*)&kv8;
      float s = 0.f;
#pragma unroll
      for (int j = 0; j < 8; j++) { float f = bf2f(u[j]); s += f * f; }
      s += __shfl_xor(s, 1);
      s += __shfl_xor(s, 2);
      s += __shfl_xor(s, 4);
      if ((tid & 7) == 0) diag_sh[r] = 0.0625f * s;   // 0.5*dn^2
    }
    // v scatter into vsT
    {
      const ushort* ve = (const ushort*)&vv;
#pragma unroll
      for (int j = 0; j < 8; j++) vsT[a8 * 8 + j][pc] = ve[j];
    }
    __syncthreads();   // [B] diag + vsT + kts visible
    // phi MFMA: out[m=64][n=32]; wave w -> m rows w*16..w*16+15
    floatx4 pacc[2] = {};
#pragma unroll
    for (int s = 0; s < 2; s++) {
      const int ar = w * 16 + l16;
      short8 af = *(const short8*)&projs[ar * 64 + ((s * 4 + quad) ^ (ar & 7)) * 8];
#pragma unroll
      for (int nj = 0; nj < 2; nj++) {
        const int br = nj * 16 + l16;
        short8 bf = *(const short8*)&kts[br * 64 + ((s * 4 + quad) ^ (br & 7)) * 8];
        pacc[nj] = __builtin_amdgcn_mfma_f32_16x16x32_bf16(af, bf, pacc[nj], 0, 0, 0);
      }
    }
    // FAVOR key epilogue -> kps (swizzled scatter)
#pragma unroll
    for (int nj = 0; nj < 2; nj++) {
      const int n = nj * 16 + l16;
      const float dgn = diag_sh[n];
#pragma unroll
      for (int r = 0; r < 4; r++) {
        const int m = w * 16 + quad * 4 + r;
        float val = (m0 + m < M_) ? ratio * expf(dn * pacc[nj][r] - dgn + 1e-4f) : 0.f;
        kps[m][(((n >> 3) ^ ((m >> 3) & 3)) << 3) | (n & 7)] = f2bf(val);
      }
    }
    __syncthreads();   // [C] kps ready
    // ctx MFMA
    const int am = w * 16 + l16;
    const int apg = quad ^ ((am >> 3) & 3);
    short8 af = *(const short8*)&kps[am][apg * 8];
#pragma unroll
    for (int et = 0; et < 4; et++) {
      const int be = et * 16 + l16;
      const int bpg = quad ^ ((be >> 3) & 3);
      short8 bf = *(const short8*)&vsT[be][bpg * 8];
      acc[et] = __builtin_amdgcn_mfma_f32_16x16x32_bf16(af, bf, acc[et], 0, 0, 0);
    }
    // ksum partial (row km, physical chunk kg; permutation within row is sum-invariant)
    {
      short8 kr = *(const short8*)&kps[km][kg * 8];
      const ushort* ku = (const ushort*)&kr;
#pragma unroll
      for (int j = 0; j < 8; j++) ksp += bf2f(ku[j]);
    }
  }
  float* pb = part + ((size_t)(bh * NS_ + ns) * 5 + mt) * 4096;
#pragma unroll
  for (int et = 0; et < 4; et++)
#pragma unroll
    for (int r = 0; r < 4; r++)
      pb[(w * 16 + quad * 4 + r) * 64 + et * 16 + l16] = acc[et][r];
  kshare[kg][km] = ksp;
  __syncthreads();
  if (tid < 64)
    kpart[((size_t)(bh * NS_ + ns) * 5 + mt) * 64 + tid] =
        kshare[0][tid] + kshare[1][tid] + kshare[2][tid] + kshare[3][tid];
}

// ---------------- reduce partials -> ctxbT bf16 [bh][64 e][288 m] + ksum[bh][PS_] -------------
// Writes the context TRANSPOSED so attn_fused can load PV B-fragments directly from
// global (16B per lane, L2-resident) with no LDS scatter and no PV-loop barriers.
__global__ __launch_bounds__(256) void ctx_reduce(const float* __restrict__ part,
                                                  const float* __restrict__ kpart,
                                                  ushort* __restrict__ ctxbT,
                                                  float* __restrict__ ksum) {
  const int bh = blockIdx.x, mt = blockIdx.y;
  const int tid = threadIdx.x;
  const int w = tid >> 6, lane = tid & 63;
  // wave w handles m-octets oc = w, w+4 within this 64-m tile; lane = e (coalesced part reads)
  for (int oc = w; oc < 8; oc += 4) {
    const int mbase = mt * 64 + oc * 8;
    if (mbase < 288) {
      float s[8] = {0.f, 0.f, 0.f, 0.f, 0.f, 0.f, 0.f, 0.f};
#pragma unroll
      for (int ns = 0; ns < NS_; ns++) {
        const float* pb = part + ((size_t)(bh * NS_ + ns) * 5 + mt) * 4096;
#pragma unroll
        for (int ml = 0; ml < 8; ml++) s[ml] += pb[(oc * 8 + ml) * 64 + lane];
      }
      ushort tmp[8];
#pragma unroll
      for (int ml = 0; ml < 8; ml++) tmp[ml] = f2bf(s[ml]);
      *(short8*)(ctxbT + ((size_t)(bh * 64 + lane)) * 288 + mbase) = *(const short8*)tmp;
    }
  }
  if (tid < 64) {
    float s = 0.f;
#pragma unroll
    for (int ns = 0; ns < NS_; ns++)
      s += kpart[((size_t)(bh * NS_ + ns) * 5 + mt) * 64 + tid];
    ksum[(size_t)bh * PS_ + mt * 64 + tid] = s;
  }
}

// ---------------- fused phi_q + dinv + attn_out ----------------
// Phase 1: stage q tile + proj, 36 MFMAs into acc[18] (As/Bs in aliased LDS).
// Phase 2 (barrier-free): per 32-m chunk, FAVOR epilogue -> per-wave qst slab
// (wave-local 16x16 transpose), A-frag from qst, B-frag direct from global ctxbT.
// dinv kept entirely in registers. LDS: 28672 + 1152 + 256 = ~30KB -> 4+ blocks/CU.
__global__ __launch_bounds__(256, 4) void attn_fused(const ushort* __restrict__ qkv,
                                                     const ushort* __restrict__ projp,
                                                     const ushort* __restrict__ ctxbT,
                                                     const float* __restrict__ ksum,
                                                     ushort* __restrict__ o) {
  __shared__ __align__(16) ushort sm[14336];  // phase1: As[64*64]@0, Bs[160*64]@4096; phase2: qst
  __shared__ float ks_sh[288];
  __shared__ float diag_sh[64];
  ushort* As = sm;
  ushort* Bs = sm + 4096;
  ushort (*qst)[40] = (ushort(*)[40])sm;      // [64][40] per-wave 16-row slabs (aliases As)
  const int bh = blockIdx.x, b = bh >> 3, h = bh & 7;
  const int n0 = blockIdx.y * 64;
  const int tid = threadIdx.x;
  const int w = tid >> 6, lane = tid & 63, l16 = lane & 15, quad = lane >> 4;
  const int rl8 = lane >> 3;
  const int lc8 = ((lane & 7) ^ (rl8 & 7)) * 8;
#pragma unroll
  for (int j = 0; j < 2; j++) {
    const int rb = w * 16 + j * 8;
    async_cp16(qkv + (size_t)(b * N_ + n0 + rb + rl8) * QKVS_ + h * 64 + lc8, As + rb * 64);
  }
#pragma unroll
  for (int j = 0; j < 5; j++) {
    const int rb = w * 40 + j * 8;
    async_cp16(projp + (size_t)(rb + rl8) * 64 + lc8, Bs + rb * 64);
  }
  for (int i = tid; i < 288; i += 256) ks_sh[i] = ksum[(size_t)bh * PS_ + i];
  __syncthreads();
  {
    const int r = w * 16 + (lane >> 2);
    const int c0 = 2 * (lane & 3);
    float s = 0.f;
#pragma unroll
    for (int cc = 0; cc < 2; cc++) {
      short8 vv = *(const short8*)&As[r * 64 + ((c0 + cc) ^ (r & 7)) * 8];
      const ushort* u = (const ushort*)&vv;
#pragma unroll
      for (int j = 0; j < 8; j++) { float f = bf2f(u[j]); s += f * f; }
    }
    s += __shfl_xor(s, 1);
    s += __shfl_xor(s, 2);
    if ((lane & 3) == 0) diag_sh[r] = 0.0625f * s;
  }
  __syncthreads();
  float dgr[4];
#pragma unroll
  for (int r = 0; r < 4; r++) dgr[r] = diag_sh[w * 16 + quad * 4 + r];
  floatx4 acc[18];
#pragma unroll
  for (int cf = 0; cf < 18; cf++) acc[cf] = (floatx4){0.f, 0.f, 0.f, 0.f};
  const int ar = w * 16 + l16;
#pragma unroll
  for (int s = 0; s < 2; s++) {
    short8 af = *(const short8*)&As[ar * 64 + ((s * 4 + quad) ^ (ar & 7)) * 8];
#pragma unroll
    for (int cf = 0; cf < 10; cf++) {
      const int br = cf * 16 + l16;
      short8 bf = *(const short8*)&Bs[br * 64 + ((s * 4 + quad) ^ (br & 7)) * 8];
      acc[cf] = __builtin_amdgcn_mfma_f32_16x16x32_bf16(af, bf, acc[cf], 0, 0, 0);
    }
  }
  __syncthreads();
#pragma unroll
  for (int j = 0; j < 4; j++) {
    const int rb = w * 32 + j * 8;
    async_cp16(projp + (size_t)(160 + rb + rl8) * 64 + lc8, Bs + rb * 64);
  }
  __syncthreads();
#pragma unroll
  for (int s = 0; s < 2; s++) {
    short8 af = *(const short8*)&As[ar * 64 + ((s * 4 + quad) ^ (ar & 7)) * 8];
#pragma unroll
    for (int cf = 10; cf < 18; cf++) {
      const int br = (cf - 10) * 16 + l16;
      short8 bf = *(const short8*)&Bs[br * 64 + ((s * 4 + quad) ^ (br & 7)) * 8];
      acc[cf] = __builtin_amdgcn_mfma_f32_16x16x32_bf16(af, bf, acc[cf], 0, 0, 0);
    }
  }
  const float dn = 0.35355339059327373f;
  const float ratio = 0.06131393394849658f;
  float mxr[4];
#pragma unroll
  for (int r = 0; r < 4; r++) {
    float mx = -1e30f;
#pragma unroll
    for (int cf = 0; cf < 18; cf++) {
      const int col = cf * 16 + l16;
      if (col < M_) mx = fmaxf(mx, dn * acc[cf][r]);
    }
    mx = fmaxf(mx, __shfl_xor(mx, 1));
    mx = fmaxf(mx, __shfl_xor(mx, 2));
    mx = fmaxf(mx, __shfl_xor(mx, 4));
    mx = fmaxf(mx, __shfl_xor(mx, 8));
    mxr[r] = mx;
  }
  __syncthreads();  // phase-1 LDS reads complete before qst alias writes
  float dacc[4] = {0.f, 0.f, 0.f, 0.f};
  floatx4 acc2[4] = {};
  const ushort* ctxrow = ctxbT + (size_t)bh * (64 * 288);
  for (int m0 = 0; m0 < 288; m0 += 32) {
    const int cf0 = m0 >> 4;
    // FAVOR epilogue for this 32-m chunk -> per-wave qst slab (wave-local transpose)
#pragma unroll
    for (int cc = 0; cc < 2; cc++) {
      const int col = m0 + cc * 16 + l16;
      const float kv = ks_sh[col];
#pragma unroll
      for (int r = 0; r < 4; r++) {
        float val = (col < M_) ? ratio * (expf(dn * acc[cf0 + cc][r] - dgr[r] - mxr[r]) + 1e-4f)
                               : 0.f;
        qst[w * 16 + quad * 4 + r][cc * 16 + l16] = f2bf(val);
        dacc[r] += val * kv;
      }
    }
    // A-frag from own wave's slab (same-wave DS order is in-order; no barrier needed)
    short8 af = *(const short8*)&qst[w * 16 + l16][quad * 8];
#pragma unroll
    for (int et = 0; et < 4; et++) {
      short8 bf = *(const short8*)(ctxrow + (size_t)(et * 16 + l16) * 288 + m0 + quad * 8);
      acc2[et] = __builtin_amdgcn_mfma_f32_16x16x32_bf16(af, bf, acc2[et], 0, 0, 0);
    }
  }
  float di[4];
#pragma unroll
  for (int r = 0; r < 4; r++) {
    float d = dacc[r];
    d += __shfl_xor(d, 1);
    d += __shfl_xor(d, 2);
    d += __shfl_xor(d, 4);
    d += __shfl_xor(d, 8);
    di[r] = 1.f / (d + 1e-8f);
  }
#pragma unroll
  for (int r = 0; r < 4; r++) {
    const int n = n0 + w * 16 + quad * 4 + r;
#pragma unroll
    for (int et = 0; et < 4; et++)
      o[((size_t)(b * N_ + n)) * 512 + h * 64 + et * 16 + l16] = f2bf(acc2[et][r] * di[r]);
  }
}

// ---------------- depthwise conv K=31, pad 15, + bias + silu; bf16 in/out ----------------
#define TN_ 16
__global__ __launch_bounds__(256) void dwconv_kernel(const ushort* __restrict__ x,
                                                     const float* __restrict__ w,
                                                     const float* __restrict__ bias,
                                                     ushort* __restrict__ out) {
  const int bid = blockIdx.x;
  const int cb = bid & 3;
  const int nb = (bid >> 2) & 127;
  const int b  = bid >> 9;
  const int c = cb * 256 + threadIdx.x;
  const int n0 = nb * TN_;
  float win[TN_ + 30];
#pragma unroll
  for (int i = 0; i < TN_ + 30; i++) {
    int nn = n0 + i - 15;
    win[i] = (nn >= 0 && nn < N_) ? bf2f(x[(size_t)(b * N_ + nn) * INNER_ + c]) : 0.f;
  }
  float wc[31];
#pragma unroll
  for (int kk = 0; kk < 31; kk++) wc[kk] = w[c * 31 + kk];
  const float bsv = bias[c];
#pragma unroll
  for (int j = 0; j < TN_; j++) {
    float acc = bsv;
#pragma unroll
    for (int kk = 0; kk < 31; kk++) acc += win[j + kk] * wc[kk];
    acc = acc / (1.f + expf(-acc));
    out[(size_t)(b * N_ + n0 + j) * INNER_ + c] = f2bf(acc);
  }
}

// ---------------- host ----------------
extern "C" void kernel_launch(void* const* d_in, const int* in_sizes, int n_in,
                              void* d_out, int out_size, void* d_ws, size_t ws_size,
                              hipStream_t stream) {
  const float* in_x  = (const float*)d_in[0];
  const float* ln1_g = (const float*)d_in[1];
  const float* ln1_b = (const float*)d_in[2];
  const float* wq    = (const float*)d_in[3];
  const float* bq    = (const float*)d_in[4];
  const float* wk    = (const float*)d_in[5];
  const float* bk    = (const float*)d_in[6];
  const float* wv    = (const float*)d_in[7];
  const float* bv    = (const float*)d_in[8];
  const float* wo    = (const float*)d_in[9];
  const float* bo    = (const float*)d_in[10];
  const float* proj  = (const float*)d_in[11];
  const float* ln2_g = (const float*)d_in[12];
  const float* ln2_b = (const float*)d_in[13];
  const float* pw1_w = (const float*)d_in[14];
  const float* pw1_b = (const float*)d_in[15];
  const float* dw_w  = (const float*)d_in[16];
  const float* dw_b  = (const float*)d_in[17];
  const float* pw2_w = (const float*)d_in[18];
  const float* pw2_b = (const float*)d_in[19];

  char* cur = (char*)d_ws;
  auto alloc = [&](size_t bytes) { char* p = cur; cur += (bytes + 255) & ~(size_t)255; return p; };
  float*  x    = (float*)alloc((size_t)T_ * D_ * 4);
  ushort* p    = (ushort*)alloc((size_t)T_ * INNER_ * 2 * 2);      // glu+conv scratch
  float*  part = (float*)alloc((size_t)32 * NS_ * 5 * 4096 * 4);
  float*  kpart= (float*)alloc((size_t)32 * NS_ * 5 * 64 * 4);
  ushort* ctxb = (ushort*)alloc((size_t)32 * 288 * 64 * 2);        // holds ctx^T [bh][64][288]
  float*  ksum = (float*)alloc((size_t)32 * PS_ * 4);
  ushort* h    = (ushort*)alloc((size_t)T_ * D_ * 2);
  ushort* qkv  = (ushort*)alloc((size_t)T_ * QKVS_ * 2);
  ushort* obuf = (ushort*)alloc((size_t)T_ * D_ * 2);
  ushort* wqkv_b = (ushort*)alloc((size_t)L_LAYERS * QKVS_ * 512 * 2);
  float*  bqkv   = (float*)alloc((size_t)L_LAYERS * QKVS_ * 4);
  ushort* wo_b = (ushort*)alloc((size_t)L_LAYERS * D_ * D_ * 2);
  ushort* pjp  = (ushort*)alloc((size_t)L_LAYERS * 320 * 64 * 2);
  ushort* p1_b = (ushort*)alloc((size_t)L_LAYERS * 2048 * D_ * 2);
  float*  pb1  = (float*)alloc((size_t)L_LAYERS * 2048 * 4);
  ushort* p2_b = (ushort*)alloc((size_t)L_LAYERS * D_ * INNER_ * 2);
  ushort* glu  = p;
  ushort* conv = p + (size_t)T_ * INNER_;

  pack_qkv_w<<<(L_LAYERS * 512 * 128 + 255) / 256, 256, 0, stream>>>((const float4*)wq, wqkv_b, 0);
  pack_qkv_w<<<(L_LAYERS * 512 * 128 + 255) / 256, 256, 0, stream>>>((const float4*)wk, wqkv_b, 512);
  pack_qkv_w<<<(L_LAYERS * 512 * 128 + 255) / 256, 256, 0, stream>>>((const float4*)wv, wqkv_b, 1024);
  pack_qkv_b<<<(L_LAYERS * QKVS_ + 255) / 256, 256, 0, stream>>>(bq, bk, bv, bqkv);
  pad_proj<<<(L_LAYERS * 320 * 64 + 255) / 256, 256, 0, stream>>>(proj, pjp);
  pack_pw1_w<<<(L_LAYERS * 2048 * 128 + 255) / 256, 256, 0, stream>>>((const float4*)pw1_w, p1_b);
  pack_pw1_b<<<(L_LAYERS * 2048 + 255) / 256, 256, 0, stream>>>(pw1_b, pb1);
  {
    int n4 = L_LAYERS * D_ * D_ / 4;
    f2bf4_kernel<<<(n4 + 255) / 256, 256, 0, stream>>>((const float4*)wo, wo_b, n4);
    n4 = L_LAYERS * D_ * INNER_ / 4;
    f2bf4_kernel<<<(n4 + 255) / 256, 256, 0, stream>>>((const float4*)pw2_w, p2_b, n4);
  }

  for (int l = 0; l < L_LAYERS; l++) {
    const ushort* wqkvl = wqkv_b + (size_t)l * QKVS_ * 512;
    const ushort* wol = wo_b + (size_t)l * D_ * D_;
    const ushort* pjl = pjp + (size_t)l * 320 * 64;
    const ushort* p1l = p1_b + (size_t)l * 2048 * D_;
    const ushort* p2l = p2_b + (size_t)l * D_ * INNER_;
    const float*  dwl = dw_w + (size_t)l * INNER_ * 31;
    const float*  dwbl = dw_b + (size_t)l * INNER_;
    const float*  xin = (l == 0) ? in_x : x;
    float* xout = (l == L_LAYERS - 1) ? (float*)d_out : x;

    ln_kernel<<<T_, 256, 0, stream>>>(xin, ln1_g + l * D_, ln1_b + l * D_, h);
    gemm_mfma<false, true, 0, 512><<<dim3(T_ / 128, QKVS_ / 128), 256, 0, stream>>>(
        h, wqkvl, bqkv + (size_t)l * QKVS_, nullptr, qkv, QKVS_);
    ctx_phi_mfma<<<dim3(32, 5, NS_), 256, 0, stream>>>(qkv, pjl, part, kpart);
    ctx_reduce<<<dim3(32, 5), 256, 0, stream>>>(part, kpart, ctxb, ksum);
    attn_fused<<<dim3(32, 32), 256, 0, stream>>>(qkv, pjl, ctxb, ksum, obuf);
    gemm_mfma<true, false, 0, 512><<<dim3(T_ / 128, 4), 256, 0, stream>>>(
        obuf, wol, bo + l * D_, xin, x, D_);
    ln_kernel<<<T_, 256, 0, stream>>>(x, ln2_g + l * D_, ln2_b + l * D_, h);
    gemm_mfma<false, true, 1, 512><<<dim3(T_ / 128, 16), 256, 0, stream>>>(
        h, p1l, pb1 + (size_t)l * 2048, nullptr, glu, INNER_);
    dwconv_kernel<<<B_ * (N_ / TN_) * 4, 256, 0, stream>>>(glu, dwl, dwbl, conv);
    gemm_mfma<true, false, 0, 1024><<<dim3(T_ / 128, 4), 256, 0, stream>>>(
        conv, p2l, pw2_b + l * D_, x, xout, D_);
  }
}

// Round 4
// 1224.958 us; speedup vs baseline: 1.1283x; 1.0018x over previous
//
#include <hip/hip_runtime.h>

// PCmer forward: bf16-MFMA; phi_k fused INTO ctx (kp never hits HBM); phi_q+dinv+attn_out fused;
// GLU fused into pw1 (interleaved weights); fused QKV; ksum fused into ctx.
// R1: attn_fused LDS 76KB->30KB, ctx pre-transposed, barrier-free PV loop.
// R2: gemm_mfma double-buffered LDS + 1-deep prefetch.
// R3: gemm_mfma depth-2 pipeline, 3 LDS buffers, counted vmcnt; ctx n-splits 8.
// R4: gemm_big 256x128 tile, per-wave 128x64 acc (0.375KB LDS/MFMA vs 0.5) for QKV+pw1;
//     dwconv TN 16->32 (read amplification 2.9x->1.9x).
// L=6, B=4, N=2048, D=512, H=8, DH=64, ID=512, M=266, INNER=1024, K=31.

#define L_LAYERS 6
#define B_ 4
#define N_ 2048
#define D_ 512
#define H_ 8
#define DH_ 64
#define M_ 266
#define INNER_ 1024
#define T_ 8192            // B*N tokens
#define PS_ 320            // padded m stride (zeros in [266,320))
#define QKVS_ 1536         // qkv row stride
#define NS_ 8              // ctx n-splits

typedef __attribute__((ext_vector_type(8))) short short8;
typedef __attribute__((ext_vector_type(4))) float floatx4;

__device__ __forceinline__ ushort f2bf(float f) {
  union { float f; uint u; } v; v.f = f;
  uint r = v.u + 0x7fffu + ((v.u >> 16) & 1u);
  return (ushort)(r >> 16);
}
__device__ __forceinline__ float bf2f(ushort u) {
  union { uint u; float f; } v; v.u = ((uint)u) << 16;
  return v.f;
}
__device__ __forceinline__ float wave_sum(float v) {
#pragma unroll
  for (int m = 1; m < 64; m <<= 1) v += __shfl_xor(v, m);
  return v;
}
// async global->LDS, 16B per lane; dest = wave-uniform base + lane*16 (src per-lane)
__device__ __forceinline__ void async_cp16(const void* g, void* l) {
  __builtin_amdgcn_global_load_lds(
      (const __attribute__((address_space(1))) void*)g,
      (__attribute__((address_space(3))) void*)l, 16, 0, 0);
}

// ---------------- weight packing ----------------
__global__ void f2bf4_kernel(const float4* __restrict__ in, ushort* __restrict__ out, int n4) {
  int i = blockIdx.x * 256 + threadIdx.x;
  if (i < n4) {
    float4 v = in[i];
    ushort4 r;
    r.x = f2bf(v.x); r.y = f2bf(v.y); r.z = f2bf(v.z); r.w = f2bf(v.w);
    *(ushort4*)(out + (size_t)i * 4) = r;
  }
}
__global__ void pack_qkv_w(const float4* __restrict__ src, ushort* __restrict__ dst, int off) {
  int i = blockIdx.x * 256 + threadIdx.x;   // L*512*128
  if (i >= L_LAYERS * 512 * 128) return;
  int l = i >> 16;
  int rem = i & 65535;
  int row = rem >> 7, c4 = rem & 127;
  float4 v = src[i];
  ushort4 r;
  r.x = f2bf(v.x); r.y = f2bf(v.y); r.z = f2bf(v.z); r.w = f2bf(v.w);
  *(ushort4*)(dst + ((size_t)l * QKVS_ + off + row) * 512 + c4 * 4) = r;
}
__global__ void pack_qkv_b(const float* __restrict__ bq, const float* __restrict__ bk,
                           const float* __restrict__ bv, float* __restrict__ dst) {
  int i = blockIdx.x * 256 + threadIdx.x;   // L*1536
  if (i >= L_LAYERS * QKVS_) return;
  int l = i / QKVS_, c = i % QKVS_;
  dst[i] = c < 512 ? bq[l * 512 + c] : (c < 1024 ? bk[l * 512 + c - 512] : bv[l * 512 + c - 1024]);
}
__global__ void pad_proj(const float* __restrict__ proj, ushort* __restrict__ dst) {
  int i = blockIdx.x * 256 + threadIdx.x;   // L*320*64
  if (i >= L_LAYERS * 320 * 64) return;
  int l = i / (320 * 64), rem = i % (320 * 64), m = rem >> 6, kk = rem & 63;
  dst[i] = (m < M_) ? f2bf(proj[((size_t)l * M_ + m) * 64 + kk]) : (ushort)0;
}
// pw1 interleave: out col c' = 32b+16s+j16 -> src row s*1024 + 16b + j16
__global__ void pack_pw1_w(const float4* __restrict__ src, ushort* __restrict__ dst) {
  int i = blockIdx.x * 256 + threadIdx.x;   // L*2048*128
  if (i >= L_LAYERS * 2048 * 128) return;
  int l = i >> 18;
  int rem = i & 262143;
  int cp = rem >> 7, c4 = rem & 127;
  int s = (cp >> 4) & 1;
  int srow = ((cp >> 5) << 4) + (cp & 15) + s * 1024;
  float4 v = src[((size_t)l * 2048 + srow) * 128 + c4];
  ushort4 r;
  r.x = f2bf(v.x); r.y = f2bf(v.y); r.z = f2bf(v.z); r.w = f2bf(v.w);
  *(ushort4*)(dst + ((size_t)l * 2048 + cp) * 512 + c4 * 4) = r;
}
__global__ void pack_pw1_b(const float* __restrict__ src, float* __restrict__ dst) {
  int i = blockIdx.x * 256 + threadIdx.x;   // L*2048
  if (i >= L_LAYERS * 2048) return;
  int l = i >> 11, cp = i & 2047;
  int s = (cp >> 4) & 1;
  int srow = ((cp >> 5) << 4) + (cp & 15) + s * 1024;
  dst[i] = src[l * 2048 + srow];
}

// ---------------- layernorm (block per token, D=512), bf16 out ----------------
__global__ __launch_bounds__(256) void ln_kernel(const float* __restrict__ x,
                                                 const float* __restrict__ g,
                                                 const float* __restrict__ b,
                                                 ushort* __restrict__ out) {
  const int t = blockIdx.x;
  const int tid = threadIdx.x;
  const float* row = x + (size_t)t * D_;
  float v0 = row[tid], v1 = row[tid + 256];
  float s1 = v0 + v1;
  float s2 = v0 * v0 + v1 * v1;
  s1 = wave_sum(s1);
  s2 = wave_sum(s2);
  __shared__ float sh1[4], sh2[4];
  int w = tid >> 6;
  if ((tid & 63) == 0) { sh1[w] = s1; sh2[w] = s2; }
  __syncthreads();
  s1 = sh1[0] + sh1[1] + sh1[2] + sh1[3];
  s2 = sh2[0] + sh2[1] + sh2[2] + sh2[3];
  float mu = s1 * (1.f / D_);
  float var = s2 * (1.f / D_) - mu * mu;
  float rs = rsqrtf(var + 1e-5f);
  out[(size_t)t * D_ + tid]       = f2bf((v0 - mu) * rs * g[tid] + b[tid]);
  out[(size_t)t * D_ + tid + 256] = f2bf((v1 - mu) * rs * g[tid + 256] + b[tid + 256]);
}

// ---------------- bf16 MFMA GEMM 128x128: depth-2 pipeline, 3 buffers, counted vmcnt --------
template <bool HAS_RES, bool OUT_BF16, int ACT, int KT>
__global__ __launch_bounds__(256) void gemm_mfma(const ushort* __restrict__ A,
                                                 const ushort* __restrict__ W,
                                                 const float* __restrict__ bias,
                                                 const float* __restrict__ res,
                                                 void* __restrict__ Cout,
                                                 int ldc) {
  constexpr int NT = KT / 32;
  __shared__ ushort As[3][128 * 32];
  __shared__ ushort Bs[3][128 * 32];
  const int tid = threadIdx.x;
  const int w = tid >> 6, lane = tid & 63;
  const int row0 = blockIdx.x * 128, col0 = blockIdx.y * 128;
  const int rl = lane >> 2;
  const int lc = ((lane & 3) ^ ((lane >> 3) & 3)) * 8;
  const ushort* gA0 = A + (size_t)(row0 + w * 32 + rl) * KT + lc;
  const ushort* gA1 = gA0 + (size_t)16 * KT;
  const ushort* gB0 = W + (size_t)(col0 + w * 32 + rl) * KT + lc;
  const ushort* gB1 = gB0 + (size_t)16 * KT;
  const int m16 = lane & 15, quad = lane >> 4;
  const int awr = (w >> 1) * 64, bwc = (w & 1) * 64;
  floatx4 acc[4][4] = {};

  auto stage = [&](int t, int buf) {
    async_cp16(gA0 + t * 32, As[buf] + w * 1024);
    async_cp16(gA1 + t * 32, As[buf] + w * 1024 + 512);
    async_cp16(gB0 + t * 32, Bs[buf] + w * 1024);
    async_cp16(gB1 + t * 32, Bs[buf] + w * 1024 + 512);
  };
  auto body = [&](int buf, bool bar2) {
    short8 af[4], bfr[4];
#pragma unroll
    for (int i = 0; i < 4; i++) {
      int r = awr + i * 16 + m16;
      af[i] = *(const short8*)&As[buf][r * 32 + (quad ^ ((r >> 1) & 3)) * 8];
    }
#pragma unroll
    for (int j = 0; j < 4; j++) {
      int r = bwc + j * 16 + m16;
      bfr[j] = *(const short8*)&Bs[buf][r * 32 + (quad ^ ((r >> 1) & 3)) * 8];
    }
    if (bar2) {
      asm volatile("s_waitcnt lgkmcnt(0)" ::: "memory");
      __builtin_amdgcn_sched_barrier(0);
      __builtin_amdgcn_s_barrier();
    }
#pragma unroll
    for (int i = 0; i < 4; i++)
#pragma unroll
      for (int j = 0; j < 4; j++)
        acc[i][j] = __builtin_amdgcn_mfma_f32_16x16x32_bf16(af[i], bfr[j], acc[i][j], 0, 0, 0);
  };

  stage(0, 0);
  stage(1, 1);
  int c = 0;
  for (int t = 0; t < NT - 2; t++) {
    int pf = c + 2; if (pf >= 3) pf -= 3;
    stage(t + 2, pf);
    asm volatile("s_waitcnt vmcnt(8)" ::: "memory");
    __builtin_amdgcn_s_barrier();
    body(c, true);
    c++; if (c >= 3) c -= 3;
  }
  asm volatile("s_waitcnt vmcnt(4)" ::: "memory");
  __builtin_amdgcn_s_barrier();
  body(c, false);
  c++; if (c >= 3) c -= 3;
  asm volatile("s_waitcnt vmcnt(0)" ::: "memory");
  __builtin_amdgcn_s_barrier();
  body(c, false);

  if (ACT == 0) {
#pragma unroll
    for (int i = 0; i < 4; i++) {
      const int r0 = row0 + awr + i * 16 + quad * 4;
#pragma unroll
      for (int j = 0; j < 4; j++) {
        const int cc = col0 + bwc + j * 16 + m16;
        const float bv = bias[cc];
#pragma unroll
        for (int r = 0; r < 4; r++) {
          float vv = acc[i][j][r] + bv;
          if (HAS_RES) vv += res[(size_t)(r0 + r) * ldc + cc];
          if (OUT_BF16) ((ushort*)Cout)[(size_t)(r0 + r) * ldc + cc] = f2bf(vv);
          else          ((float*)Cout)[(size_t)(r0 + r) * ldc + cc] = vv;
        }
      }
    }
  } else {
#pragma unroll
    for (int i = 0; i < 4; i++) {
      const int r0 = row0 + awr + i * 16 + quad * 4;
#pragma unroll
      for (int jp = 0; jp < 2; jp++) {
        const int j = jp * 2;
        const int ca = col0 + bwc + j * 16 + m16;
        const float ba = bias[ca], bg = bias[ca + 16];
        const int oc = ((col0 + bwc) >> 1) + jp * 16 + m16;
#pragma unroll
        for (int r = 0; r < 4; r++) {
          float a = acc[i][j][r] + ba;
          float g = acc[i][j + 1][r] + bg;
          float z = a / (1.f + expf(-g));
          ((ushort*)Cout)[(size_t)(r0 + r) * ldc + oc] = f2bf(z);
        }
      }
    }
  }
}

// ---------------- bf16 MFMA GEMM 256x128: per-wave 128x64 acc (higher MFMA/LDS ratio) -------
// 4 waves in 2x2; wave tile 128x64 -> 12 fragment reads feed 32 MFMAs (0.375KB/MFMA).
// Same depth-2 / 3-buffer counted-vmcnt pipeline; 6 loads per wave per stage.
template <bool OUT_BF16, int ACT, int KT>
__global__ __launch_bounds__(256, 2) void gemm_big(const ushort* __restrict__ A,
                                                   const ushort* __restrict__ W,
                                                   const float* __restrict__ bias,
                                                   void* __restrict__ Cout,
                                                   int ldc) {
  constexpr int NT = KT / 32;
  __shared__ ushort As[3][256 * 32];
  __shared__ ushort Bs[3][128 * 32];
  const int tid = threadIdx.x;
  const int w = tid >> 6, lane = tid & 63;
  const int row0 = blockIdx.x * 256, col0 = blockIdx.y * 128;
  const int rl = lane >> 2;
  const int lc = ((lane & 3) ^ ((lane >> 3) & 3)) * 8;
  // wave w stages A rows w*64 + j*16 + rl (j=0..3), B rows w*32 + j*16 + rl (j=0..1)
  const ushort* gA = A + (size_t)(row0 + w * 64 + rl) * KT + lc;
  const ushort* gB = W + (size_t)(col0 + w * 32 + rl) * KT + lc;
  const int m16 = lane & 15, quad = lane >> 4;
  const int awr = (w >> 1) * 128;   // wave row block (0 or 128)
  const int bwc = (w & 1) * 64;     // wave col block (0 or 64)
  floatx4 acc[8][4] = {};

  auto stage = [&](int t, int buf) {
#pragma unroll
    for (int j = 0; j < 4; j++)
      async_cp16(gA + ((size_t)j * 16) * KT + t * 32, As[buf] + w * 2048 + j * 512);
#pragma unroll
    for (int j = 0; j < 2; j++)
      async_cp16(gB + ((size_t)j * 16) * KT + t * 32, Bs[buf] + w * 1024 + j * 512);
  };
  auto body = [&](int buf, bool bar2) {
    short8 af[8], bfr[4];
#pragma unroll
    for (int i = 0; i < 8; i++) {
      int r = awr + i * 16 + m16;
      af[i] = *(const short8*)&As[buf][r * 32 + (quad ^ ((r >> 1) & 3)) * 8];
    }
#pragma unroll
    for (int j = 0; j < 4; j++) {
      int r = bwc + j * 16 + m16;
      bfr[j] = *(const short8*)&Bs[buf][r * 32 + (quad ^ ((r >> 1) & 3)) * 8];
    }
    if (bar2) {
      asm volatile("s_waitcnt lgkmcnt(0)" ::: "memory");
      __builtin_amdgcn_sched_barrier(0);
      __builtin_amdgcn_s_barrier();
    }
#pragma unroll
    for (int i = 0; i < 8; i++)
#pragma unroll
      for (int j = 0; j < 4; j++)
        acc[i][j] = __builtin_amdgcn_mfma_f32_16x16x32_bf16(af[i], bfr[j], acc[i][j], 0, 0, 0);
  };

  stage(0, 0);
  stage(1, 1);
  int c = 0;
  for (int t = 0; t < NT - 2; t++) {
    int pf = c + 2; if (pf >= 3) pf -= 3;
    stage(t + 2, pf);                                    // 18 in flight
    asm volatile("s_waitcnt vmcnt(12)" ::: "memory");    // step-t's 6 landed
    __builtin_amdgcn_s_barrier();
    body(c, true);
    c++; if (c >= 3) c -= 3;
  }
  asm volatile("s_waitcnt vmcnt(6)" ::: "memory");
  __builtin_amdgcn_s_barrier();
  body(c, false);
  c++; if (c >= 3) c -= 3;
  asm volatile("s_waitcnt vmcnt(0)" ::: "memory");
  __builtin_amdgcn_s_barrier();
  body(c, false);

  if (ACT == 0) {
#pragma unroll
    for (int i = 0; i < 8; i++) {
      const int r0 = row0 + awr + i * 16 + quad * 4;
#pragma unroll
      for (int j = 0; j < 4; j++) {
        const int cc = col0 + bwc + j * 16 + m16;
        const float bv = bias[cc];
#pragma unroll
        for (int r = 0; r < 4; r++) {
          float vv = acc[i][j][r] + bv;
          if (OUT_BF16) ((ushort*)Cout)[(size_t)(r0 + r) * ldc + cc] = f2bf(vv);
          else          ((float*)Cout)[(size_t)(r0 + r) * ldc + cc] = vv;
        }
      }
    }
  } else {
    // GLU epilogue on interleaved columns: z = (a+ba)*sigmoid(g+bg)
#pragma unroll
    for (int i = 0; i < 8; i++) {
      const int r0 = row0 + awr + i * 16 + quad * 4;
#pragma unroll
      for (int jp = 0; jp < 2; jp++) {
        const int j = jp * 2;
        const int ca = col0 + bwc + j * 16 + m16;
        const float ba = bias[ca], bg = bias[ca + 16];
        const int oc = ((col0 + bwc) >> 1) + jp * 16 + m16;
#pragma unroll
        for (int r = 0; r < 4; r++) {
          float a = acc[i][j][r] + ba;
          float g = acc[i][j + 1][r] + bg;
          float z = a / (1.f + expf(-g));
          ((ushort*)Cout)[(size_t)(r0 + r) * ldc + oc] = f2bf(z);
        }
      }
    }
  }
}

// ---------------- ctx with phi_k fused: kp computed in-LDS, never hits HBM ----------------
__global__ __launch_bounds__(256) void ctx_phi_mfma(const ushort* __restrict__ qkv,
                                                    const ushort* __restrict__ projp,
                                                    float* __restrict__ part,
                                                    float* __restrict__ kpart) {
  __shared__ ushort projs[64 * 64];  // proj rows m0..m0+63, XOR-chunk layout
  __shared__ ushort kts[32 * 64];    // raw k tile, XOR-chunk layout
  __shared__ ushort kps[64][40];     // phi^T [m][n swizzled]
  __shared__ ushort vsT[64][40];     // v^T  [e][n swizzled]
  __shared__ float diag_sh[32];
  __shared__ float kshare[4][64];
  const int bh = blockIdx.x, mt = blockIdx.y, ns = blockIdx.z;
  const int b = bh >> 3, h = bh & 7;
  const int m0 = mt * 64;
  const int tid = threadIdx.x;
  const int w = tid >> 6, lane = tid & 63, l16 = lane & 15, quad = lane >> 4;
  const int rl8 = lane >> 3;
  const int lc8 = ((lane & 7) ^ (rl8 & 7)) * 8;
#pragma unroll
  for (int j = 0; j < 2; j++) {
    const int rb = w * 16 + j * 8;
    async_cp16(projp + (size_t)(m0 + rb + rl8) * 64 + lc8, projs + rb * 64);
  }
  const int nn = tid >> 3;
  const int a8 = tid & 7;
  const int gn = nn >> 3, jn = nn & 7;
  const int pc = ((gn ^ (a8 & 3)) << 3) | jn;
  const int km = tid & 63, kg = tid >> 6;
  const float dn = 0.35355339059327373f;
  const float ratio = 0.06131393394849658f;
  floatx4 acc[4] = {};
  float ksp = 0.f;
  for (int nstep = 0; nstep < 2048 / NS_ / 32; nstep++) {
    const int n0 = ns * (2048 / NS_) + nstep * 32;
    {
      const int rb = w * 8;
      async_cp16(qkv + (size_t)(b * N_ + n0 + rb + rl8) * QKVS_ + 512 + h * 64 + lc8,
                 kts + rb * 64);
    }
    uint4 vv = *(const uint4*)(qkv + ((size_t)(b * N_ + n0 + nn)) * QKVS_ + 1024 + h * 64 + a8 * 8);
    __syncthreads();
    {
      const int r = tid >> 3;
      const int c = tid & 7;
      short8 kv8 = *(const short8*)&kts[r * 64 + c * 8];
      const ushort* u = (const ushort*)&kv8;
      float s = 0.f;
#pragma unroll
      for (int j = 0; j < 8; j++) { float f = bf2f(u[j]); s += f * f; }
      s += __shfl_xor(s, 1);
      s += __shfl_xor(s, 2);
      s += __shfl_xor(s, 4);
      if ((tid & 7) == 0) diag_sh[r] = 0.0625f * s;
    }
    {
      const ushort* ve = (const ushort*)&vv;
#pragma unroll
      for (int j = 0; j < 8; j++) vsT[a8 * 8 + j][pc] = ve[j];
    }
    __syncthreads();
    floatx4 pacc[2] = {};
#pragma unroll
    for (int s = 0; s < 2; s++) {
      const int ar = w * 16 + l16;
      short8 af = *(const short8*)&projs[ar * 64 + ((s * 4 + quad) ^ (ar & 7)) * 8];
#pragma unroll
      for (int nj = 0; nj < 2; nj++) {
        const int br = nj * 16 + l16;
        short8 bf = *(const short8*)&kts[br * 64 + ((s * 4 + quad) ^ (br & 7)) * 8];
        pacc[nj] = __builtin_amdgcn_mfma_f32_16x16x32_bf16(af, bf, pacc[nj], 0, 0, 0);
      }
    }
#pragma unroll
    for (int nj = 0; nj < 2; nj++) {
      const int n = nj * 16 + l16;
      const float dgn = diag_sh[n];
#pragma unroll
      for (int r = 0; r < 4; r++) {
        const int m = w * 16 + quad * 4 + r;
        float val = (m0 + m < M_) ? ratio * expf(dn * pacc[nj][r] - dgn + 1e-4f) : 0.f;
        kps[m][(((n >> 3) ^ ((m >> 3) & 3)) << 3) | (n & 7)] = f2bf(val);
      }
    }
    __syncthreads();
    const int am = w * 16 + l16;
    const int apg = quad ^ ((am >> 3) & 3);
    short8 af = *(const short8*)&kps[am][apg * 8];
#pragma unroll
    for (int et = 0; et < 4; et++) {
      const int be = et * 16 + l16;
      const int bpg = quad ^ ((be >> 3) & 3);
      short8 bf = *(const short8*)&vsT[be][bpg * 8];
      acc[et] = __builtin_amdgcn_mfma_f32_16x16x32_bf16(af, bf, acc[et], 0, 0, 0);
    }
    {
      short8 kr = *(const short8*)&kps[km][kg * 8];
      const ushort* ku = (const ushort*)&kr;
#pragma unroll
      for (int j = 0; j < 8; j++) ksp += bf2f(ku[j]);
    }
  }
  float* pb = part + ((size_t)(bh * NS_ + ns) * 5 + mt) * 4096;
#pragma unroll
  for (int et = 0; et < 4; et++)
#pragma unroll
    for (int r = 0; r < 4; r++)
      pb[(w * 16 + quad * 4 + r) * 64 + et * 16 + l16] = acc[et][r];
  kshare[kg][km] = ksp;
  __syncthreads();
  if (tid < 64)
    kpart[((size_t)(bh * NS_ + ns) * 5 + mt) * 64 + tid] =
        kshare[0][tid] + kshare[1][tid] + kshare[2][tid] + kshare[3][tid];
}

// ---------------- reduce partials -> ctxbT bf16 [bh][64 e][288 m] + ksum[bh][PS_] -------------
__global__ __launch_bounds__(256) void ctx_reduce(const float* __restrict__ part,
                                                  const float* __restrict__ kpart,
                                                  ushort* __restrict__ ctxbT,
                                                  float* __restrict__ ksum) {
  const int bh = blockIdx.x, mt = blockIdx.y;
  const int tid = threadIdx.x;
  const int w = tid >> 6, lane = tid & 63;
  for (int oc = w; oc < 8; oc += 4) {
    const int mbase = mt * 64 + oc * 8;
    if (mbase < 288) {
      float s[8] = {0.f, 0.f, 0.f, 0.f, 0.f, 0.f, 0.f, 0.f};
#pragma unroll
      for (int ns = 0; ns < NS_; ns++) {
        const float* pb = part + ((size_t)(bh * NS_ + ns) * 5 + mt) * 4096;
#pragma unroll
        for (int ml = 0; ml < 8; ml++) s[ml] += pb[(oc * 8 + ml) * 64 + lane];
      }
      ushort tmp[8];
#pragma unroll
      for (int ml = 0; ml < 8; ml++) tmp[ml] = f2bf(s[ml]);
      *(short8*)(ctxbT + ((size_t)(bh * 64 + lane)) * 288 + mbase) = *(const short8*)tmp;
    }
  }
  if (tid < 64) {
    float s = 0.f;
#pragma unroll
    for (int ns = 0; ns < NS_; ns++)
      s += kpart[((size_t)(bh * NS_ + ns) * 5 + mt) * 64 + tid];
    ksum[(size_t)bh * PS_ + mt * 64 + tid] = s;
  }
}

// ---------------- fused phi_q + dinv + attn_out ----------------
__global__ __launch_bounds__(256, 4) void attn_fused(const ushort* __restrict__ qkv,
                                                     const ushort* __restrict__ projp,
                                                     const ushort* __restrict__ ctxbT,
                                                     const float* __restrict__ ksum,
                                                     ushort* __restrict__ o) {
  __shared__ __align__(16) ushort sm[14336];  // phase1: As[64*64]@0, Bs[160*64]@4096; phase2: qst
  __shared__ float ks_sh[288];
  __shared__ float diag_sh[64];
  ushort* As = sm;
  ushort* Bs = sm + 4096;
  ushort (*qst)[40] = (ushort(*)[40])sm;
  const int bh = blockIdx.x, b = bh >> 3, h = bh & 7;
  const int n0 = blockIdx.y * 64;
  const int tid = threadIdx.x;
  const int w = tid >> 6, lane = tid & 63, l16 = lane & 15, quad = lane >> 4;
  const int rl8 = lane >> 3;
  const int lc8 = ((lane & 7) ^ (rl8 & 7)) * 8;
#pragma unroll
  for (int j = 0; j < 2; j++) {
    const int rb = w * 16 + j * 8;
    async_cp16(qkv + (size_t)(b * N_ + n0 + rb + rl8) * QKVS_ + h * 64 + lc8, As + rb * 64);
  }
#pragma unroll
  for (int j = 0; j < 5; j++) {
    const int rb = w * 40 + j * 8;
    async_cp16(projp + (size_t)(rb + rl8) * 64 + lc8, Bs + rb * 64);
  }
  for (int i = tid; i < 288; i += 256) ks_sh[i] = ksum[(size_t)bh * PS_ + i];
  __syncthreads();
  {
    const int r = w * 16 + (lane >> 2);
    const int c0 = 2 * (lane & 3);
    float s = 0.f;
#pragma unroll
    for (int cc = 0; cc < 2; cc++) {
      short8 vv = *(const short8*)&As[r * 64 + ((c0 + cc) ^ (r & 7)) * 8];
      const ushort* u = (const ushort*)&vv;
#pragma unroll
      for (int j = 0; j < 8; j++) { float f = bf2f(u[j]); s += f * f; }
    }
    s += __shfl_xor(s, 1);
    s += __shfl_xor(s, 2);
    if ((lane & 3) == 0) diag_sh[r] = 0.0625f * s;
  }
  __syncthreads();
  float dgr[4];
#pragma unroll
  for (int r = 0; r < 4; r++) dgr[r] = diag_sh[w * 16 + quad * 4 + r];
  floatx4 acc[18];
#pragma unroll
  for (int cf = 0; cf < 18; cf++) acc[cf] = (floatx4){0.f, 0.f, 0.f, 0.f};
  const int ar = w * 16 + l16;
#pragma unroll
  for (int s = 0; s < 2; s++) {
    short8 af = *(const short8*)&As[ar * 64 + ((s * 4 + quad) ^ (ar & 7)) * 8];
#pragma unroll
    for (int cf = 0; cf < 10; cf++) {
      const int br = cf * 16 + l16;
      short8 bf = *(const short8*)&Bs[br * 64 + ((s * 4 + quad) ^ (br & 7)) * 8];
      acc[cf] = __builtin_amdgcn_mfma_f32_16x16x32_bf16(af, bf, acc[cf], 0, 0, 0);
    }
  }
  __syncthreads();
#pragma unroll
  for (int j = 0; j < 4; j++) {
    const int rb = w * 32 + j * 8;
    async_cp16(projp + (size_t)(160 + rb + rl8) * 64 + lc8, Bs + rb * 64);
  }
  __syncthreads();
#pragma unroll
  for (int s = 0; s < 2; s++) {
    short8 af = *(const short8*)&As[ar * 64 + ((s * 4 + quad) ^ (ar & 7)) * 8];
#pragma unroll
    for (int cf = 10; cf < 18; cf++) {
      const int br = (cf - 10) * 16 + l16;
      short8 bf = *(const short8*)&Bs[br * 64 + ((s * 4 + quad) ^ (br & 7)) * 8];
      acc[cf] = __builtin_amdgcn_mfma_f32_16x16x32_bf16(af, bf, acc[cf], 0, 0, 0);
    }
  }
  const float dn = 0.35355339059327373f;
  const float ratio = 0.06131393394849658f;
  float mxr[4];
#pragma unroll
  for (int r = 0; r < 4; r++) {
    float mx = -1e30f;
#pragma unroll
    for (int cf = 0; cf < 18; cf++) {
      const int col = cf * 16 + l16;
      if (col < M_) mx = fmaxf(mx, dn * acc[cf][r]);
    }
    mx = fmaxf(mx, __shfl_xor(mx, 1));
    mx = fmaxf(mx, __shfl_xor(mx, 2));
    mx = fmaxf(mx, __shfl_xor(mx, 4));
    mx = fmaxf(mx, __shfl_xor(mx, 8));
    mxr[r] = mx;
  }
  __syncthreads();
  float dacc[4] = {0.f, 0.f, 0.f, 0.f};
  floatx4 acc2[4] = {};
  const ushort* ctxrow = ctxbT + (size_t)bh * (64 * 288);
  for (int m0 = 0; m0 < 288; m0 += 32) {
    const int cf0 = m0 >> 4;
#pragma unroll
    for (int cc = 0; cc < 2; cc++) {
      const int col = m0 + cc * 16 + l16;
      const float kv = ks_sh[col];
#pragma unroll
      for (int r = 0; r < 4; r++) {
        float val = (col < M_) ? ratio * (expf(dn * acc[cf0 + cc][r] - dgr[r] - mxr[r]) + 1e-4f)
                               : 0.f;
        qst[w * 16 + quad * 4 + r][cc * 16 + l16] = f2bf(val);
        dacc[r] += val * kv;
      }
    }
    short8 af = *(const short8*)&qst[w * 16 + l16][quad * 8];
#pragma unroll
    for (int et = 0; et < 4; et++) {
      short8 bf = *(const short8*)(ctxrow + (size_t)(et * 16 + l16) * 288 + m0 + quad * 8);
      acc2[et] = __builtin_amdgcn_mfma_f32_16x16x32_bf16(af, bf, acc2[et], 0, 0, 0);
    }
  }
  float di[4];
#pragma unroll
  for (int r = 0; r < 4; r++) {
    float d = dacc[r];
    d += __shfl_xor(d, 1);
    d += __shfl_xor(d, 2);
    d += __shfl_xor(d, 4);
    d += __shfl_xor(d, 8);
    di[r] = 1.f / (d + 1e-8f);
  }
#pragma unroll
  for (int r = 0; r < 4; r++) {
    const int n = n0 + w * 16 + quad * 4 + r;
#pragma unroll
    for (int et = 0; et < 4; et++)
      o[((size_t)(b * N_ + n)) * 512 + h * 64 + et * 16 + l16] = f2bf(acc2[et][r] * di[r]);
  }
}

// ---------------- depthwise conv K=31, pad 15, + bias + silu; bf16 in/out ----------------
#define TN_ 32
__global__ __launch_bounds__(256) void dwconv_kernel(const ushort* __restrict__ x,
                                                     const float* __restrict__ w,
                                                     const float* __restrict__ bias,
                                                     ushort* __restrict__ out) {
  const int bid = blockIdx.x;
  const int cb = bid & 3;
  const int nb = (bid >> 2) & (N_ / TN_ - 1);
  const int b  = bid >> 8;
  const int c = cb * 256 + threadIdx.x;
  const int n0 = nb * TN_;
  float win[TN_ + 30];
#pragma unroll
  for (int i = 0; i < TN_ + 30; i++) {
    int nn = n0 + i - 15;
    win[i] = (nn >= 0 && nn < N_) ? bf2f(x[(size_t)(b * N_ + nn) * INNER_ + c]) : 0.f;
  }
  float wc[31];
#pragma unroll
  for (int kk = 0; kk < 31; kk++) wc[kk] = w[c * 31 + kk];
  const float bsv = bias[c];
#pragma unroll
  for (int j = 0; j < TN_; j++) {
    float acc = bsv;
#pragma unroll
    for (int kk = 0; kk < 31; kk++) acc += win[j + kk] * wc[kk];
    acc = acc / (1.f + expf(-acc));
    out[(size_t)(b * N_ + n0 + j) * INNER_ + c] = f2bf(acc);
  }
}

// ---------------- host ----------------
extern "C" void kernel_launch(void* const* d_in, const int* in_sizes, int n_in,
                              void* d_out, int out_size, void* d_ws, size_t ws_size,
                              hipStream_t stream) {
  const float* in_x  = (const float*)d_in[0];
  const float* ln1_g = (const float*)d_in[1];
  const float* ln1_b = (const float*)d_in[2];
  const float* wq    = (const float*)d_in[3];
  const float* bq    = (const float*)d_in[4];
  const float* wk    = (const float*)d_in[5];
  const float* bk    = (const float*)d_in[6];
  const float* wv    = (const float*)d_in[7];
  const float* bv    = (const float*)d_in[8];
  const float* wo    = (const float*)d_in[9];
  const float* bo    = (const float*)d_in[10];
  const float* proj  = (const float*)d_in[11];
  const float* ln2_g = (const float*)d_in[12];
  const float* ln2_b = (const float*)d_in[13];
  const float* pw1_w = (const float*)d_in[14];
  const float* pw1_b = (const float*)d_in[15];
  const float* dw_w  = (const float*)d_in[16];
  const float* dw_b  = (const float*)d_in[17];
  const float* pw2_w = (const float*)d_in[18];
  const float* pw2_b = (const float*)d_in[19];

  char* cur = (char*)d_ws;
  auto alloc = [&](size_t bytes) { char* p = cur; cur += (bytes + 255) & ~(size_t)255; return p; };
  float*  x    = (float*)alloc((size_t)T_ * D_ * 4);
  ushort* p    = (ushort*)alloc((size_t)T_ * INNER_ * 2 * 2);      // glu+conv scratch
  float*  part = (float*)alloc((size_t)32 * NS_ * 5 * 4096 * 4);
  float*  kpart= (float*)alloc((size_t)32 * NS_ * 5 * 64 * 4);
  ushort* ctxb = (ushort*)alloc((size_t)32 * 288 * 64 * 2);        // holds ctx^T [bh][64][288]
  float*  ksum = (float*)alloc((size_t)32 * PS_ * 4);
  ushort* h    = (ushort*)alloc((size_t)T_ * D_ * 2);
  ushort* qkv  = (ushort*)alloc((size_t)T_ * QKVS_ * 2);
  ushort* obuf = (ushort*)alloc((size_t)T_ * D_ * 2);
  ushort* wqkv_b = (ushort*)alloc((size_t)L_LAYERS * QKVS_ * 512 * 2);
  float*  bqkv   = (float*)alloc((size_t)L_LAYERS * QKVS_ * 4);
  ushort* wo_b = (ushort*)alloc((size_t)L_LAYERS * D_ * D_ * 2);
  ushort* pjp  = (ushort*)alloc((size_t)L_LAYERS * 320 * 64 * 2);
  ushort* p1_b = (ushort*)alloc((size_t)L_LAYERS * 2048 * D_ * 2);
  float*  pb1  = (float*)alloc((size_t)L_LAYERS * 2048 * 4);
  ushort* p2_b = (ushort*)alloc((size_t)L_LAYERS * D_ * INNER_ * 2);
  ushort* glu  = p;
  ushort* conv = p + (size_t)T_ * INNER_;

  pack_qkv_w<<<(L_LAYERS * 512 * 128 + 255) / 256, 256, 0, stream>>>((const float4*)wq, wqkv_b, 0);
  pack_qkv_w<<<(L_LAYERS * 512 * 128 + 255) / 256, 256, 0, stream>>>((const float4*)wk, wqkv_b, 512);
  pack_qkv_w<<<(L_LAYERS * 512 * 128 + 255) / 256, 256, 0, stream>>>((const float4*)wv, wqkv_b, 1024);
  pack_qkv_b<<<(L_LAYERS * QKVS_ + 255) / 256, 256, 0, stream>>>(bq, bk, bv, bqkv);
  pad_proj<<<(L_LAYERS * 320 * 64 + 255) / 256, 256, 0, stream>>>(proj, pjp);
  pack_pw1_w<<<(L_LAYERS * 2048 * 128 + 255) / 256, 256, 0, stream>>>((const float4*)pw1_w, p1_b);
  pack_pw1_b<<<(L_LAYERS * 2048 + 255) / 256, 256, 0, stream>>>(pw1_b, pb1);
  {
    int n4 = L_LAYERS * D_ * D_ / 4;
    f2bf4_kernel<<<(n4 + 255) / 256, 256, 0, stream>>>((const float4*)wo, wo_b, n4);
    n4 = L_LAYERS * D_ * INNER_ / 4;
    f2bf4_kernel<<<(n4 + 255) / 256, 256, 0, stream>>>((const float4*)pw2_w, p2_b, n4);
  }

  for (int l = 0; l < L_LAYERS; l++) {
    const ushort* wqkvl = wqkv_b + (size_t)l * QKVS_ * 512;
    const ushort* wol = wo_b + (size_t)l * D_ * D_;
    const ushort* pjl = pjp + (size_t)l * 320 * 64;
    const ushort* p1l = p1_b + (size_t)l * 2048 * D_;
    const ushort* p2l = p2_b + (size_t)l * D_ * INNER_;
    const float*  dwl = dw_w + (size_t)l * INNER_ * 31;
    const float*  dwbl = dw_b + (size_t)l * INNER_;
    const float*  xin = (l == 0) ? in_x : x;
    float* xout = (l == L_LAYERS - 1) ? (float*)d_out : x;

    ln_kernel<<<T_, 256, 0, stream>>>(xin, ln1_g + l * D_, ln1_b + l * D_, h);
    gemm_big<true, 0, 512><<<dim3(T_ / 256, QKVS_ / 128), 256, 0, stream>>>(
        h, wqkvl, bqkv + (size_t)l * QKVS_, qkv, QKVS_);
    ctx_phi_mfma<<<dim3(32, 5, NS_), 256, 0, stream>>>(qkv, pjl, part, kpart);
    ctx_reduce<<<dim3(32, 5), 256, 0, stream>>>(part, kpart, ctxb, ksum);
    attn_fused<<<dim3(32, 32), 256, 0, stream>>>(qkv, pjl, ctxb, ksum, obuf);
    gemm_mfma<true, false, 0, 512><<<dim3(T_ / 128, 4), 256, 0, stream>>>(
        obuf, wol, bo + l * D_, xin, x, D_);
    ln_kernel<<<T_, 256, 0, stream>>>(x, ln2_g + l * D_, ln2_b + l * D_, h);
    gemm_big<true, 1, 512><<<dim3(T_ / 256, 16), 256, 0, stream>>>(
        h, p1l, pb1 + (size_t)l * 2048, glu, INNER_);
    dwconv_kernel<<<B_ * (N_ / TN_) * 4, 256, 0, stream>>>(glu, dwl, dwbl, conv);
    gemm_mfma<true, false, 0, 1024><<<dim3(T_ / 128, 4), 256, 0, stream>>>(
        conv, p2l, pw2_b + l * D_, x, xout, D_);
  }
}